// Round 3
// baseline (568.771 us; speedup 1.0000x reference)
//
#include <hip/hip_runtime.h>
#include <hip/hip_bf16.h>
#include <math.h>

typedef unsigned short u16;
typedef __attribute__((ext_vector_type(8))) short bf16x8;
typedef __attribute__((ext_vector_type(4))) float f32x4;
typedef __attribute__((ext_vector_type(4))) u16 u16x4;

#define S_LEN   1536
#define HID     2880
#define NH      64
#define NKV     8
#define DH      64
#define QKV_N   5120   // 64*64 + 2*8*64
#define QDIM    4096   // 64*64
#define KVDIM   512    // 8*64
#define SMSCALE 0.125f
#define EPSV    1e-5f

__device__ __forceinline__ float b2f(u16 u) {
    unsigned int v = ((unsigned int)u) << 16;
    float f; __builtin_memcpy(&f, &v, 4); return f;
}
__device__ __forceinline__ u16 f2b(float f) {
    __hip_bfloat16 h = __float2bfloat16(f);
    return *reinterpret_cast<u16*>(&h);
}
__device__ __forceinline__ void gld16(const u16* g, u16* l) {
    __builtin_amdgcn_global_load_lds(
        (const __attribute__((address_space(1))) unsigned int*)g,
        (__attribute__((address_space(3))) unsigned int*)l, 16, 0, 0);
}

// ---------------- 0. fp32 -> bf16 convert (for weights) ----------------
__global__ __launch_bounds__(256) void conv_bf16_kernel(
    const float* __restrict__ src, u16* __restrict__ dst, int n4)
{
    int i = blockIdx.x * 256 + threadIdx.x;
    if (i >= n4) return;
    float4 v = ((const float4*)src)[i];
    u16x4 o;
    o.x = f2b(v.x); o.y = f2b(v.y); o.z = f2b(v.z); o.w = f2b(v.w);
    ((u16x4*)dst)[i] = o;
}

// ---------------- 1. RMSNorm (fp32 in -> bf16 out) ----------------
__global__ __launch_bounds__(256) void rmsnorm_kernel(
    const float* __restrict__ x, const float* __restrict__ ns, u16* __restrict__ t)
{
    const int s = blockIdx.x;
    const int tid = threadIdx.x;
    const float* xr = x + (size_t)s * HID;
    float ss = 0.f;
    for (int i = tid; i < HID; i += 256) { float v = xr[i]; ss += v * v; }
    for (int off = 32; off > 0; off >>= 1) ss += __shfl_down(ss, off);
    __shared__ float red[4];
    if ((tid & 63) == 0) red[tid >> 6] = ss;
    __syncthreads();
    float tot = red[0] + red[1] + red[2] + red[3];
    float scale = rsqrtf(tot / (float)HID + EPSV);
    u16* tr = t + (size_t)s * HID;
    for (int i = tid; i < HID; i += 256)
        tr[i] = f2b(xr[i] * scale * ns[i]);
}

// ---------------- 2. YaRN RoPE tables (fp64 to match ref) ----------------
__global__ __launch_bounds__(256) void rope_table_kernel(float* __restrict__ cosT, float* __restrict__ sinT)
{
    int idx = blockIdx.x * 256 + threadIdx.x;
    if (idx >= S_LEN * 32) return;
    int s = idx >> 5, i = idx & 31;
    const double PI2 = 6.283185307179586476925286766559;
    double base = 150000.0;
    double freq = pow(base, (double)(2 * i) / 64.0);
    double conc = 0.1 * log(32.0) + 1.0;
    double low  = 32.0 * log(4096.0 / (32.0 * PI2)) / log(base);
    double high = 32.0 * log(4096.0 / (1.0  * PI2)) / log(base);
    double interp = 1.0 / (32.0 * freq);
    double extrap = 1.0 / freq;
    double ramp = ((double)i - low) / (high - low);
    double msk = 1.0 - fmin(fmax(ramp, 0.0), 1.0);
    double invf = interp * (1.0 - msk) + extrap * msk;
    double ang = (double)s * invf;
    cosT[idx] = (float)(cos(ang) * conc);
    sinT[idx] = (float)(sin(ang) * conc);
}

// ---------------- 3. GEMM  C[M,N] = A[M,K](bf16) * B[N,K]^T(bf16) + bias (+resid), fp32 out ----------------
__global__ __launch_bounds__(256) void gemm_bt_kernel(
    const u16* __restrict__ A, const u16* __restrict__ B,
    const float* __restrict__ bias, const float* __restrict__ resid,
    float* __restrict__ C, int M, int N, int K)
{
    __shared__ __align__(16) u16 sA[128 * 32];
    __shared__ __align__(16) u16 sB[128 * 32];
    const int tid  = threadIdx.x;
    const int wave = tid >> 6, lane = tid & 63;
    const int quad = lane >> 4, l16 = lane & 15;
    const int bm = blockIdx.y * 128, bn = blockIdx.x * 128;
    const int wm = (wave >> 1) * 64, wn = (wave & 1) * 64;

    const int r0   = wave * 32;
    const int lrow = lane >> 2;
    const int lcol = (lane & 3) * 8;

    const u16* gA0 = A + (size_t)(bm + r0 + lrow) * K + lcol;
    const u16* gA1 = gA0 + (size_t)16 * K;
    int br0 = bn + r0 + lrow;      if (br0 > N - 1) br0 = N - 1;
    int br1 = bn + r0 + 16 + lrow; if (br1 > N - 1) br1 = N - 1;
    const u16* gB0 = B + (size_t)br0 * K + lcol;
    const u16* gB1 = B + (size_t)br1 * K + lcol;

    u16* lA0 = sA + r0 * 32;        u16* lA1 = sA + (r0 + 16) * 32;
    u16* lB0 = sB + r0 * 32;        u16* lB1 = sB + (r0 + 16) * 32;

    f32x4 acc[4][4];
    #pragma unroll
    for (int mt = 0; mt < 4; mt++)
        #pragma unroll
        for (int nt = 0; nt < 4; nt++)
            acc[mt][nt] = (f32x4){0.f, 0.f, 0.f, 0.f};

    for (int k0 = 0; k0 < K; k0 += 32) {
        gld16(gA0 + k0, lA0);
        gld16(gA1 + k0, lA1);
        gld16(gB0 + k0, lB0);
        gld16(gB1 + k0, lB1);
        __syncthreads();
        bf16x8 av[4], bv[4];
        #pragma unroll
        for (int mt = 0; mt < 4; mt++)
            av[mt] = *(const bf16x8*)(sA + (wm + mt * 16 + l16) * 32 + quad * 8);
        #pragma unroll
        for (int nt = 0; nt < 4; nt++)
            bv[nt] = *(const bf16x8*)(sB + (wn + nt * 16 + l16) * 32 + quad * 8);
        #pragma unroll
        for (int mt = 0; mt < 4; mt++)
            #pragma unroll
            for (int nt = 0; nt < 4; nt++)
                acc[mt][nt] = __builtin_amdgcn_mfma_f32_16x16x32_bf16(av[mt], bv[nt], acc[mt][nt], 0, 0, 0);
        __syncthreads();
    }

    #pragma unroll
    for (int mt = 0; mt < 4; mt++) {
        #pragma unroll
        for (int nt = 0; nt < 4; nt++) {
            int col = bn + wn + nt * 16 + l16;
            if (col < N) {
                float bi = bias[col];
                int row0 = bm + wm + mt * 16 + quad * 4;
                #pragma unroll
                for (int r = 0; r < 4; r++) {
                    float v = acc[mt][nt][r] + bi;
                    size_t idx = (size_t)(row0 + r) * N + col;
                    if (resid) v += resid[idx];
                    C[idx] = v;
                }
            }
        }
    }
}

// ---------------- 4. RoPE apply + split to q/k/v bf16 ----------------
__global__ __launch_bounds__(256) void rope_apply_kernel(
    const float* __restrict__ qkv, const float* __restrict__ cosT, const float* __restrict__ sinT,
    u16* __restrict__ q_r, u16* __restrict__ k_r, u16* __restrict__ v_r)
{
    int idx = blockIdx.x * 256 + threadIdx.x;       // s * 5120 + hh*64 + i, hh in [0,80)
    if (idx >= S_LEN * 80 * 64) return;
    int s  = idx / 5120;
    int rem = idx - s * 5120;
    int hh = rem >> 6;
    int i  = rem & 63;
    const float* row = qkv + (size_t)s * QKV_N;
    if (hh < 64) {                      // Q heads
        int off = hh * 64, j = i & 31;
        float x1 = row[off + j], x2 = row[off + 32 + j];
        float c = cosT[s * 32 + j], sn = sinT[s * 32 + j];
        float val = (i < 32) ? (x1 * c - x2 * sn) : (x2 * c + x1 * sn);
        q_r[(size_t)s * QDIM + off + i] = f2b(val);
    } else if (hh < 72) {               // K heads
        int kh = hh - 64, off = QDIM + kh * 64, j = i & 31;
        float x1 = row[off + j], x2 = row[off + 32 + j];
        float c = cosT[s * 32 + j], sn = sinT[s * 32 + j];
        float val = (i < 32) ? (x1 * c - x2 * sn) : (x2 * c + x1 * sn);
        k_r[(size_t)s * KVDIM + kh * 64 + i] = f2b(val);
    } else {                            // V heads (no rope)
        int vh = hh - 72, off = QDIM + KVDIM + vh * 64;
        v_r[(size_t)s * KVDIM + vh * 64 + i] = f2b(row[off + i]);
    }
}

// ---------------- 5. Flash attention w/ sinks, causal, GQA (kv = h % 8) ----------------
__global__ __launch_bounds__(256) void attn_kernel(
    const u16* __restrict__ q_r, const u16* __restrict__ k_r, const u16* __restrict__ v_r,
    const float* __restrict__ sinks, u16* __restrict__ o)
{
    __shared__ __align__(16) u16 sK[32 * 72];    // keys x d, pad 72
    __shared__ __align__(16) u16 sVt[64 * 40];   // d x keys, pad 40
    __shared__ __align__(16) u16 sP[4 * 16 * 40];// per-wave 16 x 32, pad 40

    const int qt = blockIdx.x, h = blockIdx.y;
    const int kvh = h & 7;
    const int tid = threadIdx.x, wave = tid >> 6, lane = tid & 63;
    const int quad = lane >> 4, l16 = lane & 15;

    const int qrow = qt * 64 + wave * 16 + l16;
    const u16* qp = q_r + (size_t)qrow * QDIM + h * 64 + quad * 8;
    bf16x8 aq0 = *(const bf16x8*)(qp);
    bf16x8 aq1 = *(const bf16x8*)(qp + 32);

    float m_i[4], l_i[4];
    f32x4 acc[4];
    float sinkv = sinks[h];
    #pragma unroll
    for (int r = 0; r < 4; r++) { m_i[r] = sinkv; l_i[r] = 1.0f; }
    #pragma unroll
    for (int dt = 0; dt < 4; dt++) acc[dt] = (f32x4){0.f, 0.f, 0.f, 0.f};

    u16* sPw = sP + wave * 16 * 40;
    const int srow = tid >> 3;            // 0..31
    const int scol = (tid & 7) * 8;       // 0..56
    const int qbase = qt * 64 + wave * 16 + quad * 4;

    const int kend = qt * 64 + 64;
    for (int j0 = 0; j0 < kend; j0 += 32) {
        __syncthreads();
        // stage K rows [j0, j0+32)
        uint4 kv = *(const uint4*)(k_r + (size_t)(j0 + srow) * KVDIM + kvh * 64 + scol);
        *(uint4*)(sK + srow * 72 + scol) = kv;
        // stage V transposed
        uint4 vv = *(const uint4*)(v_r + (size_t)(j0 + srow) * KVDIM + kvh * 64 + scol);
        const u16* vp = (const u16*)&vv;
        #pragma unroll
        for (int j = 0; j < 8; j++) sVt[(scol + j) * 40 + srow] = vp[j];
        __syncthreads();

        // QK^T : 16 queries x 32 keys per wave
        f32x4 sc[2];
        #pragma unroll
        for (int nt = 0; nt < 2; nt++) {
            const u16* kp = sK + (nt * 16 + l16) * 72 + quad * 8;
            bf16x8 bk0 = *(const bf16x8*)(kp);
            bf16x8 bk1 = *(const bf16x8*)(kp + 32);
            f32x4 s0 = (f32x4){0.f, 0.f, 0.f, 0.f};
            s0 = __builtin_amdgcn_mfma_f32_16x16x32_bf16(aq0, bk0, s0, 0, 0, 0);
            s0 = __builtin_amdgcn_mfma_f32_16x16x32_bf16(aq1, bk1, s0, 0, 0, 0);
            sc[nt] = s0;
        }
        // online softmax per row (rows quad*4+r, cols l16 / 16+l16)
        #pragma unroll
        for (int r = 0; r < 4; r++) {
            int qi = qbase + r;
            float v0 = sc[0][r] * SMSCALE;
            float v1 = sc[1][r] * SMSCALE;
            int kc = j0 + l16;
            if (kc > qi)      v0 = -INFINITY;
            if (kc + 16 > qi) v1 = -INFINITY;
            float mx = fmaxf(v0, v1);
            mx = fmaxf(mx, __shfl_xor(mx, 1));
            mx = fmaxf(mx, __shfl_xor(mx, 2));
            mx = fmaxf(mx, __shfl_xor(mx, 4));
            mx = fmaxf(mx, __shfl_xor(mx, 8));
            float mnew = fmaxf(m_i[r], mx);
            float alpha = __expf(m_i[r] - mnew);
            float p0 = __expf(v0 - mnew);
            float p1 = __expf(v1 - mnew);
            float ps = p0 + p1;
            ps += __shfl_xor(ps, 1);
            ps += __shfl_xor(ps, 2);
            ps += __shfl_xor(ps, 4);
            ps += __shfl_xor(ps, 8);
            l_i[r] = l_i[r] * alpha + ps;
            m_i[r] = mnew;
            sPw[(quad * 4 + r) * 40 + l16]      = f2b(p0);
            sPw[(quad * 4 + r) * 40 + 16 + l16] = f2b(p1);
            #pragma unroll
            for (int dt = 0; dt < 4; dt++) acc[dt][r] *= alpha;
        }
        __threadfence_block();   // order sP writes before cross-lane reads (wave-internal)
        // PV : P (16x32) * V (32x64)
        bf16x8 ap = *(const bf16x8*)(sPw + l16 * 40 + quad * 8);
        #pragma unroll
        for (int dt = 0; dt < 4; dt++) {
            bf16x8 bv = *(const bf16x8*)(sVt + (dt * 16 + l16) * 40 + quad * 8);
            acc[dt] = __builtin_amdgcn_mfma_f32_16x16x32_bf16(ap, bv, acc[dt], 0, 0, 0);
        }
    }

    #pragma unroll
    for (int dt = 0; dt < 4; dt++) {
        #pragma unroll
        for (int r = 0; r < 4; r++) {
            float val = acc[dt][r] / l_i[r];
            size_t idx = (size_t)(qt * 64 + wave * 16 + quad * 4 + r) * QDIM + h * 64 + dt * 16 + l16;
            o[idx] = f2b(val);
        }
    }
}

// ---------------- launch ----------------
extern "C" void kernel_launch(void* const* d_in, const int* in_sizes, int n_in,
                              void* d_out, int out_size, void* d_ws, size_t ws_size,
                              hipStream_t stream)
{
    const float* x          = (const float*)d_in[0];
    const float* sinks      = (const float*)d_in[1];
    const float* norm_scale = (const float*)d_in[2];
    const float* qkv_w      = (const float*)d_in[3];
    const float* qkv_b      = (const float*)d_in[4];
    const float* out_w      = (const float*)d_in[5];
    const float* out_b      = (const float*)d_in[6];
    float* out = (float*)d_out;

    char* ws = (char*)d_ws;
    // Phase A (through GEMM1):   t @0 (8.85MB), qkv_w_bf @8,847,360 (29.49MB), qkv @38,338,560 (31.46MB)
    // Phase B (rope_apply on):   q_r/k_r/v_r/o overlay [0, 28.3MB); out_w_bf overlays qkv region.
    u16*   t        = (u16*)  (ws);                    // 1536*2880*2   =  8,847,360
    u16*   qkv_w_bf = (u16*)  (ws + 8847360);          // 5120*2880*2   = 29,491,200
    float* qkv      = (float*)(ws + 38338560);         // 1536*5120*4   = 31,457,280
    u16*   out_w_bf = (u16*)  (ws + 38338560);         // 2880*4096*2   = 23,592,960 (after rope_apply)
    u16*   q_r      = (u16*)  (ws);                    // 1536*4096*2   = 12,582,912 (after GEMM1)
    u16*   k_r      = (u16*)  (ws + 12582912);         // 1536*512*2    =  1,572,864
    u16*   v_r      = (u16*)  (ws + 14155776);         //               =  1,572,864
    u16*   o        = (u16*)  (ws + 15728640);         // 1536*4096*2   = 12,582,912 (ends 28,311,552)
    float* cosT     = (float*)(ws + 69795840);         // 1536*32*4     =    196,608
    float* sinT     = (float*)(ws + 69992448);         //               =    196,608 (total 70,189,056)

    rmsnorm_kernel<<<S_LEN, 256, 0, stream>>>(x, norm_scale, t);
    conv_bf16_kernel<<<(QKV_N * HID / 4 + 255) / 256, 256, 0, stream>>>(qkv_w, qkv_w_bf, QKV_N * HID / 4);
    rope_table_kernel<<<(S_LEN * 32) / 256, 256, 0, stream>>>(cosT, sinT);
    gemm_bt_kernel<<<dim3(QKV_N / 128, S_LEN / 128), 256, 0, stream>>>(
        t, qkv_w_bf, qkv_b, nullptr, qkv, S_LEN, QKV_N, HID);
    rope_apply_kernel<<<(S_LEN * 80 * 64) / 256, 256, 0, stream>>>(qkv, cosT, sinT, q_r, k_r, v_r);
    conv_bf16_kernel<<<(HID * QDIM / 4 + 255) / 256, 256, 0, stream>>>(out_w, out_w_bf, HID * QDIM / 4);
    attn_kernel<<<dim3(S_LEN / 64, NH), 256, 0, stream>>>(q_r, k_r, v_r, sinks, o);
    gemm_bt_kernel<<<dim3((HID + 127) / 128, S_LEN / 128), 256, 0, stream>>>(
        o, out_w_bf, out_b, x, out, S_LEN, HID, QDIM);
}

// Round 4
// 452.171 us; speedup vs baseline: 1.2579x; 1.2579x over previous
//
#include <hip/hip_runtime.h>
#include <hip/hip_bf16.h>
#include <math.h>

typedef unsigned short u16;
typedef __attribute__((ext_vector_type(8))) short bf16x8;
typedef __attribute__((ext_vector_type(4))) float f32x4;
typedef __attribute__((ext_vector_type(4))) u16 u16x4;

#define S_LEN   1536
#define HID     2880
#define NH      64
#define NKV     8
#define DH      64
#define QKV_N   5120   // 64*64 + 2*8*64
#define QDIM    4096   // 64*64
#define KVDIM   512    // 8*64
#define SMSCALE 0.125f
#define EPSV    1e-5f

__device__ __forceinline__ float b2f(u16 u) {
    unsigned int v = ((unsigned int)u) << 16;
    float f; __builtin_memcpy(&f, &v, 4); return f;
}
__device__ __forceinline__ u16 f2b(float f) {
    __hip_bfloat16 h = __float2bfloat16(f);
    return *reinterpret_cast<u16*>(&h);
}
__device__ __forceinline__ void gld16(const u16* g, u16* l) {
    __builtin_amdgcn_global_load_lds(
        (const __attribute__((address_space(1))) unsigned int*)g,
        (__attribute__((address_space(3))) unsigned int*)l, 16, 0, 0);
}

// ---------------- 0. fp32 -> bf16 convert (for weights) ----------------
__global__ __launch_bounds__(256) void conv_bf16_kernel(
    const float* __restrict__ src, u16* __restrict__ dst, int n4)
{
    int i = blockIdx.x * 256 + threadIdx.x;
    if (i >= n4) return;
    float4 v = ((const float4*)src)[i];
    u16x4 o;
    o.x = f2b(v.x); o.y = f2b(v.y); o.z = f2b(v.z); o.w = f2b(v.w);
    ((u16x4*)dst)[i] = o;
}

// ---------------- 1. RMSNorm (fp32 in -> bf16 out) ----------------
__global__ __launch_bounds__(256) void rmsnorm_kernel(
    const float* __restrict__ x, const float* __restrict__ ns, u16* __restrict__ t)
{
    const int s = blockIdx.x;
    const int tid = threadIdx.x;
    const float* xr = x + (size_t)s * HID;
    float ss = 0.f;
    for (int i = tid; i < HID; i += 256) { float v = xr[i]; ss += v * v; }
    for (int off = 32; off > 0; off >>= 1) ss += __shfl_down(ss, off);
    __shared__ float red[4];
    if ((tid & 63) == 0) red[tid >> 6] = ss;
    __syncthreads();
    float tot = red[0] + red[1] + red[2] + red[3];
    float scale = rsqrtf(tot / (float)HID + EPSV);
    u16* tr = t + (size_t)s * HID;
    for (int i = tid; i < HID; i += 256)
        tr[i] = f2b(xr[i] * scale * ns[i]);
}

// ---------------- 2. YaRN RoPE tables (fp64 to match ref) ----------------
__global__ __launch_bounds__(256) void rope_table_kernel(float* __restrict__ cosT, float* __restrict__ sinT)
{
    int idx = blockIdx.x * 256 + threadIdx.x;
    if (idx >= S_LEN * 32) return;
    int s = idx >> 5, i = idx & 31;
    const double PI2 = 6.283185307179586476925286766559;
    double base = 150000.0;
    double freq = pow(base, (double)(2 * i) / 64.0);
    double conc = 0.1 * log(32.0) + 1.0;
    double low  = 32.0 * log(4096.0 / (32.0 * PI2)) / log(base);
    double high = 32.0 * log(4096.0 / (1.0  * PI2)) / log(base);
    double interp = 1.0 / (32.0 * freq);
    double extrap = 1.0 / freq;
    double ramp = ((double)i - low) / (high - low);
    double msk = 1.0 - fmin(fmax(ramp, 0.0), 1.0);
    double invf = interp * (1.0 - msk) + extrap * msk;
    double ang = (double)s * invf;
    cosT[idx] = (float)(cos(ang) * conc);
    sinT[idx] = (float)(sin(ang) * conc);
}

// ---------------- 3. GEMM  C[M,N] = A[M,K](bf16) * B[N,K]^T(bf16) + bias (+resid), fp32 out ----------------
__global__ __launch_bounds__(256) void gemm_bt_kernel(
    const u16* __restrict__ A, const u16* __restrict__ B,
    const float* __restrict__ bias, const float* __restrict__ resid,
    float* __restrict__ C, int M, int N, int K)
{
    __shared__ __align__(16) u16 sA[128 * 32];
    __shared__ __align__(16) u16 sB[128 * 32];
    const int tid  = threadIdx.x;
    const int wave = tid >> 6, lane = tid & 63;
    const int quad = lane >> 4, l16 = lane & 15;
    const int bm = blockIdx.y * 128, bn = blockIdx.x * 128;
    const int wm = (wave >> 1) * 64, wn = (wave & 1) * 64;

    const int r0   = wave * 32;
    const int lrow = lane >> 2;
    const int lcol = (lane & 3) * 8;

    const u16* gA0 = A + (size_t)(bm + r0 + lrow) * K + lcol;
    const u16* gA1 = gA0 + (size_t)16 * K;
    int br0 = bn + r0 + lrow;      if (br0 > N - 1) br0 = N - 1;
    int br1 = bn + r0 + 16 + lrow; if (br1 > N - 1) br1 = N - 1;
    const u16* gB0 = B + (size_t)br0 * K + lcol;
    const u16* gB1 = B + (size_t)br1 * K + lcol;

    u16* lA0 = sA + r0 * 32;        u16* lA1 = sA + (r0 + 16) * 32;
    u16* lB0 = sB + r0 * 32;        u16* lB1 = sB + (r0 + 16) * 32;

    f32x4 acc[4][4];
    #pragma unroll
    for (int mt = 0; mt < 4; mt++)
        #pragma unroll
        for (int nt = 0; nt < 4; nt++)
            acc[mt][nt] = (f32x4){0.f, 0.f, 0.f, 0.f};

    for (int k0 = 0; k0 < K; k0 += 32) {
        gld16(gA0 + k0, lA0);
        gld16(gA1 + k0, lA1);
        gld16(gB0 + k0, lB0);
        gld16(gB1 + k0, lB1);
        __syncthreads();
        bf16x8 av[4], bv[4];
        #pragma unroll
        for (int mt = 0; mt < 4; mt++)
            av[mt] = *(const bf16x8*)(sA + (wm + mt * 16 + l16) * 32 + quad * 8);
        #pragma unroll
        for (int nt = 0; nt < 4; nt++)
            bv[nt] = *(const bf16x8*)(sB + (wn + nt * 16 + l16) * 32 + quad * 8);
        #pragma unroll
        for (int mt = 0; mt < 4; mt++)
            #pragma unroll
            for (int nt = 0; nt < 4; nt++)
                acc[mt][nt] = __builtin_amdgcn_mfma_f32_16x16x32_bf16(av[mt], bv[nt], acc[mt][nt], 0, 0, 0);
        __syncthreads();
    }

    #pragma unroll
    for (int mt = 0; mt < 4; mt++) {
        #pragma unroll
        for (int nt = 0; nt < 4; nt++) {
            int col = bn + wn + nt * 16 + l16;
            if (col < N) {
                float bi = bias[col];
                int row0 = bm + wm + mt * 16 + quad * 4;
                #pragma unroll
                for (int r = 0; r < 4; r++) {
                    float v = acc[mt][nt][r] + bi;
                    size_t idx = (size_t)(row0 + r) * N + col;
                    if (resid) v += resid[idx];
                    C[idx] = v;
                }
            }
        }
    }
}

// ---------------- 4. RoPE apply + split to q/k/v bf16 ----------------
__global__ __launch_bounds__(256) void rope_apply_kernel(
    const float* __restrict__ qkv, const float* __restrict__ cosT, const float* __restrict__ sinT,
    u16* __restrict__ q_r, u16* __restrict__ k_r, u16* __restrict__ v_r)
{
    int idx = blockIdx.x * 256 + threadIdx.x;       // s * 5120 + hh*64 + i, hh in [0,80)
    if (idx >= S_LEN * 80 * 64) return;
    int s  = idx / 5120;
    int rem = idx - s * 5120;
    int hh = rem >> 6;
    int i  = rem & 63;
    const float* row = qkv + (size_t)s * QKV_N;
    if (hh < 64) {                      // Q heads
        int off = hh * 64, j = i & 31;
        float x1 = row[off + j], x2 = row[off + 32 + j];
        float c = cosT[s * 32 + j], sn = sinT[s * 32 + j];
        float val = (i < 32) ? (x1 * c - x2 * sn) : (x2 * c + x1 * sn);
        q_r[(size_t)s * QDIM + off + i] = f2b(val);
    } else if (hh < 72) {               // K heads
        int kh = hh - 64, off = QDIM + kh * 64, j = i & 31;
        float x1 = row[off + j], x2 = row[off + 32 + j];
        float c = cosT[s * 32 + j], sn = sinT[s * 32 + j];
        float val = (i < 32) ? (x1 * c - x2 * sn) : (x2 * c + x1 * sn);
        k_r[(size_t)s * KVDIM + kh * 64 + i] = f2b(val);
    } else {                            // V heads (no rope)
        int vh = hh - 72, off = QDIM + KVDIM + vh * 64;
        v_r[(size_t)s * KVDIM + vh * 64 + i] = f2b(row[off + i]);
    }
}

// ---------------- 4b. V transpose: v_r[s][kvh*64+d] -> vt[(kvh*64+d)][s] ----------------
__global__ __launch_bounds__(256) void vt_kernel(
    const u16* __restrict__ v_r, u16* __restrict__ vt)
{
    __shared__ u16 tile[64][72];
    const int s0 = blockIdx.x * 64;
    const int kvh = blockIdx.y;
    const int tid = threadIdx.x;
    const int r = tid >> 3;          // 0..31
    const int c = (tid & 7) * 8;     // 0..56

    #pragma unroll
    for (int rr = 0; rr < 64; rr += 32) {
        uint4 vv = *(const uint4*)(v_r + (size_t)(s0 + r + rr) * KVDIM + kvh * 64 + c);
        const u16* p = (const u16*)&vv;
        #pragma unroll
        for (int j = 0; j < 8; j++) tile[c + j][r + rr] = p[j];
    }
    __syncthreads();
    #pragma unroll
    for (int rr = 0; rr < 64; rr += 32) {
        uint4 ov;
        u16* p = (u16*)&ov;
        #pragma unroll
        for (int j = 0; j < 8; j++) p[j] = tile[r + rr][c + j];
        *(uint4*)(vt + (size_t)(kvh * 64 + r + rr) * S_LEN + s0 + c) = ov;
    }
}

// ---------------- 5. Flash attention w/ sinks, causal, GQA (kv = h % 8) ----------------
// Grid (12, 64): block bx processes q-tiles bx and 23-bx (balanced: 25 chunk-iters each).
__global__ __launch_bounds__(256) void attn_kernel(
    const u16* __restrict__ q_r, const u16* __restrict__ k_r, const u16* __restrict__ vt,
    const float* __restrict__ sinks, u16* __restrict__ o)
{
    __shared__ __align__(16) u16 sK[64 * 72];     // keys x d, pad 72
    __shared__ __align__(16) u16 sVt[64 * 72];    // d x keys, pad 72
    __shared__ __align__(16) u16 sP[4 * 16 * 72]; // per-wave 16 x 64, pad 72

    const int bx = blockIdx.x, h = blockIdx.y;
    const int kvh = h & 7;
    const int tid = threadIdx.x, wave = tid >> 6, lane = tid & 63;
    const int quad = lane >> 4, l16 = lane & 15;
    const int srow = tid >> 3;            // 0..31
    const int scol = (tid & 7) * 8;       // 0..56
    u16* sPw = sP + wave * 16 * 72;
    const float sinkv = sinks[h];

    for (int phase = 0; phase < 2; ++phase) {
        const int qt = phase ? (23 - bx) : bx;
        const int qrow = qt * 64 + wave * 16 + l16;
        const u16* qp = q_r + (size_t)qrow * QDIM + h * 64 + quad * 8;
        bf16x8 aq0 = *(const bf16x8*)(qp);
        bf16x8 aq1 = *(const bf16x8*)(qp + 32);

        float m_i[4], l_i[4];
        f32x4 acc[4];
        #pragma unroll
        for (int r = 0; r < 4; r++) { m_i[r] = sinkv; l_i[r] = 1.0f; }
        #pragma unroll
        for (int dt = 0; dt < 4; dt++) acc[dt] = (f32x4){0.f, 0.f, 0.f, 0.f};

        const int qbase = qt * 64 + wave * 16 + quad * 4;
        const int kend = qt * 64 + 64;

        for (int j0 = 0; j0 < kend; j0 += 64) {
            __syncthreads();
            // stage K rows [j0, j0+64) and V^T cols [j0, j0+64)
            #pragma unroll
            for (int rr = 0; rr < 64; rr += 32) {
                *(uint4*)(sK + (srow + rr) * 72 + scol) =
                    *(const uint4*)(k_r + (size_t)(j0 + srow + rr) * KVDIM + kvh * 64 + scol);
                *(uint4*)(sVt + (srow + rr) * 72 + scol) =
                    *(const uint4*)(vt + (size_t)(kvh * 64 + srow + rr) * S_LEN + j0 + scol);
            }
            __syncthreads();

            // QK^T : 16 queries x 64 keys per wave
            f32x4 sc[4];
            #pragma unroll
            for (int nt = 0; nt < 4; nt++) {
                const u16* kp = sK + (nt * 16 + l16) * 72 + quad * 8;
                bf16x8 bk0 = *(const bf16x8*)(kp);
                bf16x8 bk1 = *(const bf16x8*)(kp + 32);
                f32x4 s0 = (f32x4){0.f, 0.f, 0.f, 0.f};
                s0 = __builtin_amdgcn_mfma_f32_16x16x32_bf16(aq0, bk0, s0, 0, 0, 0);
                s0 = __builtin_amdgcn_mfma_f32_16x16x32_bf16(aq1, bk1, s0, 0, 0, 0);
                sc[nt] = s0;
            }

            // online softmax per row (row = quad*4+r, cols nt*16 + l16)
            #pragma unroll
            for (int r = 0; r < 4; r++) {
                int qi = qbase + r;
                float v[4];
                #pragma unroll
                for (int nt = 0; nt < 4; nt++) {
                    v[nt] = sc[nt][r] * SMSCALE;
                    if (j0 + nt * 16 + l16 > qi) v[nt] = -INFINITY;
                }
                float mx = fmaxf(fmaxf(v[0], v[1]), fmaxf(v[2], v[3]));
                mx = fmaxf(mx, __shfl_xor(mx, 1));
                mx = fmaxf(mx, __shfl_xor(mx, 2));
                mx = fmaxf(mx, __shfl_xor(mx, 4));
                mx = fmaxf(mx, __shfl_xor(mx, 8));
                float mnew = fmaxf(m_i[r], mx);
                float alpha = __expf(m_i[r] - mnew);
                float p[4], ps;
                #pragma unroll
                for (int nt = 0; nt < 4; nt++) p[nt] = __expf(v[nt] - mnew);
                ps = (p[0] + p[1]) + (p[2] + p[3]);
                ps += __shfl_xor(ps, 1);
                ps += __shfl_xor(ps, 2);
                ps += __shfl_xor(ps, 4);
                ps += __shfl_xor(ps, 8);
                l_i[r] = l_i[r] * alpha + ps;
                m_i[r] = mnew;
                #pragma unroll
                for (int nt = 0; nt < 4; nt++)
                    sPw[(quad * 4 + r) * 72 + nt * 16 + l16] = f2b(p[nt]);
                #pragma unroll
                for (int dt = 0; dt < 4; dt++) acc[dt][r] *= alpha;
            }
            __threadfence_block();   // order sP writes before cross-lane reads (wave-internal)

            // PV : P (16x64) * V (64x64)
            bf16x8 ap0 = *(const bf16x8*)(sPw + l16 * 72 + quad * 8);
            bf16x8 ap1 = *(const bf16x8*)(sPw + l16 * 72 + 32 + quad * 8);
            #pragma unroll
            for (int dt = 0; dt < 4; dt++) {
                const u16* vp = sVt + (dt * 16 + l16) * 72 + quad * 8;
                bf16x8 bv0 = *(const bf16x8*)(vp);
                bf16x8 bv1 = *(const bf16x8*)(vp + 32);
                acc[dt] = __builtin_amdgcn_mfma_f32_16x16x32_bf16(ap0, bv0, acc[dt], 0, 0, 0);
                acc[dt] = __builtin_amdgcn_mfma_f32_16x16x32_bf16(ap1, bv1, acc[dt], 0, 0, 0);
            }
        }

        #pragma unroll
        for (int dt = 0; dt < 4; dt++) {
            #pragma unroll
            for (int r = 0; r < 4; r++) {
                float val = acc[dt][r] / l_i[r];
                size_t idx = (size_t)(qt * 64 + wave * 16 + quad * 4 + r) * QDIM + h * 64 + dt * 16 + l16;
                o[idx] = f2b(val);
            }
        }
    }
}

// ---------------- launch ----------------
extern "C" void kernel_launch(void* const* d_in, const int* in_sizes, int n_in,
                              void* d_out, int out_size, void* d_ws, size_t ws_size,
                              hipStream_t stream)
{
    const float* x          = (const float*)d_in[0];
    const float* sinks      = (const float*)d_in[1];
    const float* norm_scale = (const float*)d_in[2];
    const float* qkv_w      = (const float*)d_in[3];
    const float* qkv_b      = (const float*)d_in[4];
    const float* out_w      = (const float*)d_in[5];
    const float* out_b      = (const float*)d_in[6];
    float* out = (float*)d_out;

    char* ws = (char*)d_ws;
    // Phase A (through GEMM1):   t @0 (8.85MB), qkv_w_bf @8,847,360 (29.49MB), qkv @38,338,560 (31.46MB)
    // Phase B (rope_apply on):   q_r/k_r/v_r/o/vt overlay [0, 29.9MB); out_w_bf overlays qkv region.
    u16*   t        = (u16*)  (ws);                    // 1536*2880*2   =  8,847,360
    u16*   qkv_w_bf = (u16*)  (ws + 8847360);          // 5120*2880*2   = 29,491,200
    float* qkv      = (float*)(ws + 38338560);         // 1536*5120*4   = 31,457,280
    u16*   out_w_bf = (u16*)  (ws + 38338560);         // 2880*4096*2   = 23,592,960 (after rope_apply)
    u16*   q_r      = (u16*)  (ws);                    // 1536*4096*2   = 12,582,912 (after GEMM1)
    u16*   k_r      = (u16*)  (ws + 12582912);         // 1536*512*2    =  1,572,864
    u16*   v_r      = (u16*)  (ws + 14155776);         //               =  1,572,864
    u16*   o        = (u16*)  (ws + 15728640);         // 1536*4096*2   = 12,582,912
    u16*   vt       = (u16*)  (ws + 28311552);         // 512*1536*2    =  1,572,864 (ends 29,884,416)
    float* cosT     = (float*)(ws + 69795840);         // 1536*32*4     =    196,608
    float* sinT     = (float*)(ws + 69992448);         //               =    196,608 (total 70,189,056)

    rmsnorm_kernel<<<S_LEN, 256, 0, stream>>>(x, norm_scale, t);
    conv_bf16_kernel<<<(QKV_N * HID / 4 + 255) / 256, 256, 0, stream>>>(qkv_w, qkv_w_bf, QKV_N * HID / 4);
    rope_table_kernel<<<(S_LEN * 32) / 256, 256, 0, stream>>>(cosT, sinT);
    gemm_bt_kernel<<<dim3(QKV_N / 128, S_LEN / 128), 256, 0, stream>>>(
        t, qkv_w_bf, qkv_b, nullptr, qkv, S_LEN, QKV_N, HID);
    rope_apply_kernel<<<(S_LEN * 80 * 64) / 256, 256, 0, stream>>>(qkv, cosT, sinT, q_r, k_r, v_r);
    vt_kernel<<<dim3(S_LEN / 64, NKV), 256, 0, stream>>>(v_r, vt);
    conv_bf16_kernel<<<(HID * QDIM / 4 + 255) / 256, 256, 0, stream>>>(out_w, out_w_bf, HID * QDIM / 4);
    attn_kernel<<<dim3(12, NH), 256, 0, stream>>>(q_r, k_r, vt, sinks, o);
    gemm_bt_kernel<<<dim3((HID + 127) / 128, S_LEN / 128), 256, 0, stream>>>(
        o, out_w_bf, out_b, x, out, S_LEN, HID, QDIM);
}

// Round 6
// 393.937 us; speedup vs baseline: 1.4438x; 1.1478x over previous
//
#include <hip/hip_runtime.h>
#include <hip/hip_bf16.h>
#include <math.h>

typedef unsigned short u16;
typedef __attribute__((ext_vector_type(8))) short bf16x8;
typedef __attribute__((ext_vector_type(4))) float f32x4;
typedef __attribute__((ext_vector_type(4))) u16 u16x4;

#define S_LEN   1536
#define HID     2880
#define NH      64
#define NKV     8
#define DH      64
#define QKV_N   5120   // 64*64 + 2*8*64
#define QDIM    4096   // 64*64
#define KVDIM   512    // 8*64
#define SMSCALE 0.125f
#define EPSV    1e-5f

__device__ __forceinline__ float b2f(u16 u) {
    unsigned int v = ((unsigned int)u) << 16;
    float f; __builtin_memcpy(&f, &v, 4); return f;
}
__device__ __forceinline__ u16 f2b(float f) {
    __hip_bfloat16 h = __float2bfloat16(f);
    return *reinterpret_cast<u16*>(&h);
}
__device__ __forceinline__ void gld16(const u16* g, u16* l) {
    __builtin_amdgcn_global_load_lds(
        (const __attribute__((address_space(1))) unsigned int*)g,
        (__attribute__((address_space(3))) unsigned int*)l, 16, 0, 0);
}
// s_waitcnt immediates (gfx9 encoding: vm[3:0],[15:14]; exp[6:4]; lgkm[11:8])
#define WAIT_VM4()   __builtin_amdgcn_s_waitcnt(0xF74)  // vmcnt<=4, lgkm/exp free
#define WAIT_VM0()   __builtin_amdgcn_s_waitcnt(0xF70)  // vmcnt<=0
#define WAIT_LGKM0() __builtin_amdgcn_s_waitcnt(0xC07F) // lgkmcnt<=0, vm/exp free

// ---------------- 0. fp32 -> bf16 convert (for weights) ----------------
__global__ __launch_bounds__(256) void conv_bf16_kernel(
    const float* __restrict__ src, u16* __restrict__ dst, int n4)
{
    int i = blockIdx.x * 256 + threadIdx.x;
    if (i >= n4) return;
    float4 v = ((const float4*)src)[i];
    u16x4 o;
    o.x = f2b(v.x); o.y = f2b(v.y); o.z = f2b(v.z); o.w = f2b(v.w);
    ((u16x4*)dst)[i] = o;
}

// ---------------- 1. RMSNorm (fp32 in -> bf16 out) ----------------
__global__ __launch_bounds__(256) void rmsnorm_kernel(
    const float* __restrict__ x, const float* __restrict__ ns, u16* __restrict__ t)
{
    const int s = blockIdx.x;
    const int tid = threadIdx.x;
    const float* xr = x + (size_t)s * HID;
    float ss = 0.f;
    for (int i = tid; i < HID; i += 256) { float v = xr[i]; ss += v * v; }
    for (int off = 32; off > 0; off >>= 1) ss += __shfl_down(ss, off);
    __shared__ float red[4];
    if ((tid & 63) == 0) red[tid >> 6] = ss;
    __syncthreads();
    float tot = red[0] + red[1] + red[2] + red[3];
    float scale = rsqrtf(tot / (float)HID + EPSV);
    u16* tr = t + (size_t)s * HID;
    for (int i = tid; i < HID; i += 256)
        tr[i] = f2b(xr[i] * scale * ns[i]);
}

// ---------------- 2. YaRN RoPE tables (fp64 to match ref) ----------------
__global__ __launch_bounds__(256) void rope_table_kernel(float* __restrict__ cosT, float* __restrict__ sinT)
{
    int idx = blockIdx.x * 256 + threadIdx.x;
    if (idx >= S_LEN * 32) return;
    int s = idx >> 5, i = idx & 31;
    const double PI2 = 6.283185307179586476925286766559;
    double base = 150000.0;
    double freq = pow(base, (double)(2 * i) / 64.0);
    double conc = 0.1 * log(32.0) + 1.0;
    double low  = 32.0 * log(4096.0 / (32.0 * PI2)) / log(base);
    double high = 32.0 * log(4096.0 / (1.0  * PI2)) / log(base);
    double interp = 1.0 / (32.0 * freq);
    double extrap = 1.0 / freq;
    double ramp = ((double)i - low) / (high - low);
    double msk = 1.0 - fmin(fmax(ramp, 0.0), 1.0);
    double invf = interp * (1.0 - msk) + extrap * msk;
    double ang = (double)s * invf;
    cosT[idx] = (float)(cos(ang) * conc);
    sinT[idx] = (float)(sin(ang) * conc);
}

// ---------------- 3. split-K GEMM  Cp[z][M,N](bf16) = A[M,K](bf16) * B[N,K]^T(bf16), K-chunk per z ----------------
// Double-buffered LDS + raw s_barrier + manual vmcnt (no __syncthreads drain).
// NOTE: partials for z=0,1 MUST be contiguous: Cp + z*M*N elements.
__global__ __launch_bounds__(256) void gemm_bt_split_kernel(
    const u16* __restrict__ A, const u16* __restrict__ B, u16* __restrict__ Cp,
    int M, int N, int K, int kchunk)
{
    __shared__ __align__(16) u16 sA[2][128 * 32];
    __shared__ __align__(16) u16 sB[2][128 * 32];
    const int tid  = threadIdx.x;
    const int wave = tid >> 6, lane = tid & 63;
    const int quad = lane >> 4, l16 = lane & 15;
    const int bm = blockIdx.y * 128, bn = blockIdx.x * 128;
    const int wm = (wave >> 1) * 64, wn = (wave & 1) * 64;
    const int kb = blockIdx.z * kchunk;
    u16* C = Cp + (size_t)blockIdx.z * M * N;

    const int r0   = wave * 32;
    const int lrow = lane >> 2;
    const int lcol = (lane & 3) * 8;

    const u16* gA0 = A + (size_t)(bm + r0 + lrow) * K + lcol + kb;
    const u16* gA1 = gA0 + (size_t)16 * K;
    int br0 = bn + r0 + lrow;      if (br0 > N - 1) br0 = N - 1;
    int br1 = bn + r0 + 16 + lrow; if (br1 > N - 1) br1 = N - 1;
    const u16* gB0 = B + (size_t)br0 * K + lcol + kb;
    const u16* gB1 = B + (size_t)br1 * K + lcol + kb;

    f32x4 acc[4][4];
    #pragma unroll
    for (int mt = 0; mt < 4; mt++)
        #pragma unroll
        for (int nt = 0; nt < 4; nt++)
            acc[mt][nt] = (f32x4){0.f, 0.f, 0.f, 0.f};

    auto stage = [&](int buf, int koff) {
        gld16(gA0 + koff, &sA[buf][r0 * 32]);
        gld16(gA1 + koff, &sA[buf][(r0 + 16) * 32]);
        gld16(gB0 + koff, &sB[buf][r0 * 32]);
        gld16(gB1 + koff, &sB[buf][(r0 + 16) * 32]);
    };
    auto compute = [&](int buf) {
        bf16x8 av[4], bv[4];
        #pragma unroll
        for (int mt = 0; mt < 4; mt++)
            av[mt] = *(const bf16x8*)(&sA[buf][(wm + mt * 16 + l16) * 32 + quad * 8]);
        #pragma unroll
        for (int nt = 0; nt < 4; nt++)
            bv[nt] = *(const bf16x8*)(&sB[buf][(wn + nt * 16 + l16) * 32 + quad * 8]);
        #pragma unroll
        for (int mt = 0; mt < 4; mt++)
            #pragma unroll
            for (int nt = 0; nt < 4; nt++)
                acc[mt][nt] = __builtin_amdgcn_mfma_f32_16x16x32_bf16(av[mt], bv[nt], acc[mt][nt], 0, 0, 0);
    };

    const int niter = kchunk / 32;
    stage(0, 0);
    int cur = 0;
    for (int i = 0; i < niter - 1; ++i) {
        stage(cur ^ 1, (i + 1) * 32);     // prefetch next tile (4 loads in flight on top of cur's 4)
        WAIT_VM4();                        // my cur-tile loads landed
        __builtin_amdgcn_s_barrier();      // everyone's cur-tile landed
        compute(cur);
        WAIT_LGKM0();                      // my reads of cur done
        __builtin_amdgcn_s_barrier();      // everyone's reads done -> cur may be overwritten
        cur ^= 1;
    }
    WAIT_VM0();
    __builtin_amdgcn_s_barrier();
    compute(cur);

    #pragma unroll
    for (int mt = 0; mt < 4; mt++) {
        #pragma unroll
        for (int nt = 0; nt < 4; nt++) {
            int col = bn + wn + nt * 16 + l16;
            if (col < N) {
                int row0 = bm + wm + mt * 16 + quad * 4;
                #pragma unroll
                for (int r = 0; r < 4; r++)
                    C[(size_t)(row0 + r) * N + col] = f2b(acc[mt][nt][r]);
            }
        }
    }
}

// ---------------- 4. RoPE apply + split-K reduce + bias + split to q/k/v bf16 ----------------
__global__ __launch_bounds__(256) void rope_apply_kernel(
    const u16* __restrict__ p0, const u16* __restrict__ p1, const float* __restrict__ bias,
    const float* __restrict__ cosT, const float* __restrict__ sinT,
    u16* __restrict__ q_r, u16* __restrict__ k_r, u16* __restrict__ v_r)
{
    int idx = blockIdx.x * 256 + threadIdx.x;       // s * 5120 + hh*64 + i, hh in [0,80)
    if (idx >= S_LEN * 80 * 64) return;
    int s  = idx / 5120;
    int rem = idx - s * 5120;
    int hh = rem >> 6;
    int i  = rem & 63;
    const u16* r0p = p0 + (size_t)s * QKV_N;
    const u16* r1p = p1 + (size_t)s * QKV_N;
    #define QKVV(o) (b2f(r0p[o]) + b2f(r1p[o]) + bias[o])
    if (hh < 64) {                      // Q heads
        int off = hh * 64, j = i & 31;
        float x1 = QKVV(off + j), x2 = QKVV(off + 32 + j);
        float c = cosT[s * 32 + j], sn = sinT[s * 32 + j];
        float val = (i < 32) ? (x1 * c - x2 * sn) : (x2 * c + x1 * sn);
        q_r[(size_t)s * QDIM + off + i] = f2b(val);
    } else if (hh < 72) {               // K heads
        int kh = hh - 64, off = QDIM + kh * 64, j = i & 31;
        float x1 = QKVV(off + j), x2 = QKVV(off + 32 + j);
        float c = cosT[s * 32 + j], sn = sinT[s * 32 + j];
        float val = (i < 32) ? (x1 * c - x2 * sn) : (x2 * c + x1 * sn);
        k_r[(size_t)s * KVDIM + kh * 64 + i] = f2b(val);
    } else {                            // V heads (no rope)
        int vh = hh - 72, off = QDIM + KVDIM + vh * 64;
        v_r[(size_t)s * KVDIM + vh * 64 + i] = f2b(QKVV(off + i));
    }
    #undef QKVV
}

// ---------------- 4b. V transpose: v_r[s][kvh*64+d] -> vt[(kvh*64+d)][s] ----------------
__global__ __launch_bounds__(256) void vt_kernel(
    const u16* __restrict__ v_r, u16* __restrict__ vt)
{
    __shared__ u16 tile[64][72];
    const int s0 = blockIdx.x * 64;
    const int kvh = blockIdx.y;
    const int tid = threadIdx.x;
    const int r = tid >> 3;          // 0..31
    const int c = (tid & 7) * 8;     // 0..56

    #pragma unroll
    for (int rr = 0; rr < 64; rr += 32) {
        uint4 vv = *(const uint4*)(v_r + (size_t)(s0 + r + rr) * KVDIM + kvh * 64 + c);
        const u16* p = (const u16*)&vv;
        #pragma unroll
        for (int j = 0; j < 8; j++) tile[c + j][r + rr] = p[j];
    }
    __syncthreads();
    #pragma unroll
    for (int rr = 0; rr < 64; rr += 32) {
        uint4 ov;
        u16* p = (u16*)&ov;
        #pragma unroll
        for (int j = 0; j < 8; j++) p[j] = tile[r + rr][c + j];
        *(uint4*)(vt + (size_t)(kvh * 64 + r + rr) * S_LEN + s0 + c) = ov;
    }
}

// ---------------- 5. Flash attention w/ sinks, causal, GQA (kv = h % 8) ----------------
// Grid (12, 64): block bx processes q-tiles bx and 23-bx (balanced: 25 chunk-iters each).
__global__ __launch_bounds__(256) void attn_kernel(
    const u16* __restrict__ q_r, const u16* __restrict__ k_r, const u16* __restrict__ vt,
    const float* __restrict__ sinks, u16* __restrict__ o)
{
    __shared__ __align__(16) u16 sK[64 * 72];     // keys x d, pad 72
    __shared__ __align__(16) u16 sVt[64 * 72];    // d x keys, pad 72
    __shared__ __align__(16) u16 sP[4 * 16 * 72]; // per-wave 16 x 64, pad 72

    const int bx = blockIdx.x, h = blockIdx.y;
    const int kvh = h & 7;
    const int tid = threadIdx.x, wave = tid >> 6, lane = tid & 63;
    const int quad = lane >> 4, l16 = lane & 15;
    const int srow = tid >> 3;            // 0..31
    const int scol = (tid & 7) * 8;       // 0..56
    u16* sPw = sP + wave * 16 * 72;
    const float sinkv = sinks[h];

    for (int phase = 0; phase < 2; ++phase) {
        const int qt = phase ? (23 - bx) : bx;
        const int qrow = qt * 64 + wave * 16 + l16;
        const u16* qp = q_r + (size_t)qrow * QDIM + h * 64 + quad * 8;
        bf16x8 aq0 = *(const bf16x8*)(qp);
        bf16x8 aq1 = *(const bf16x8*)(qp + 32);

        float m_i[4], l_i[4];
        f32x4 acc[4];
        #pragma unroll
        for (int r = 0; r < 4; r++) { m_i[r] = sinkv; l_i[r] = 1.0f; }
        #pragma unroll
        for (int dt = 0; dt < 4; dt++) acc[dt] = (f32x4){0.f, 0.f, 0.f, 0.f};

        const int qbase = qt * 64 + wave * 16 + quad * 4;
        const int kend = qt * 64 + 64;

        for (int j0 = 0; j0 < kend; j0 += 64) {
            __syncthreads();
            // stage K rows [j0, j0+64) and V^T cols [j0, j0+64)
            #pragma unroll
            for (int rr = 0; rr < 64; rr += 32) {
                *(uint4*)(sK + (srow + rr) * 72 + scol) =
                    *(const uint4*)(k_r + (size_t)(j0 + srow + rr) * KVDIM + kvh * 64 + scol);
                *(uint4*)(sVt + (srow + rr) * 72 + scol) =
                    *(const uint4*)(vt + (size_t)(kvh * 64 + srow + rr) * S_LEN + j0 + scol);
            }
            __syncthreads();

            // QK^T : 16 queries x 64 keys per wave
            f32x4 sc[4];
            #pragma unroll
            for (int nt = 0; nt < 4; nt++) {
                const u16* kp = sK + (nt * 16 + l16) * 72 + quad * 8;
                bf16x8 bk0 = *(const bf16x8*)(kp);
                bf16x8 bk1 = *(const bf16x8*)(kp + 32);
                f32x4 s0 = (f32x4){0.f, 0.f, 0.f, 0.f};
                s0 = __builtin_amdgcn_mfma_f32_16x16x32_bf16(aq0, bk0, s0, 0, 0, 0);
                s0 = __builtin_amdgcn_mfma_f32_16x16x32_bf16(aq1, bk1, s0, 0, 0, 0);
                sc[nt] = s0;
            }

            // online softmax per row (row = quad*4+r, cols nt*16 + l16)
            #pragma unroll
            for (int r = 0; r < 4; r++) {
                int qi = qbase + r;
                float v[4];
                #pragma unroll
                for (int nt = 0; nt < 4; nt++) {
                    v[nt] = sc[nt][r] * SMSCALE;
                    if (j0 + nt * 16 + l16 > qi) v[nt] = -INFINITY;
                }
                float mx = fmaxf(fmaxf(v[0], v[1]), fmaxf(v[2], v[3]));
                mx = fmaxf(mx, __shfl_xor(mx, 1));
                mx = fmaxf(mx, __shfl_xor(mx, 2));
                mx = fmaxf(mx, __shfl_xor(mx, 4));
                mx = fmaxf(mx, __shfl_xor(mx, 8));
                float mnew = fmaxf(m_i[r], mx);
                float alpha = __expf(m_i[r] - mnew);
                float p[4], ps;
                #pragma unroll
                for (int nt = 0; nt < 4; nt++) p[nt] = __expf(v[nt] - mnew);
                ps = (p[0] + p[1]) + (p[2] + p[3]);
                ps += __shfl_xor(ps, 1);
                ps += __shfl_xor(ps, 2);
                ps += __shfl_xor(ps, 4);
                ps += __shfl_xor(ps, 8);
                l_i[r] = l_i[r] * alpha + ps;
                m_i[r] = mnew;
                #pragma unroll
                for (int nt = 0; nt < 4; nt++)
                    sPw[(quad * 4 + r) * 72 + nt * 16 + l16] = f2b(p[nt]);
                #pragma unroll
                for (int dt = 0; dt < 4; dt++) acc[dt][r] *= alpha;
            }
            __threadfence_block();   // order sP writes before cross-lane reads (wave-internal)

            // PV : P (16x64) * V (64x64)
            bf16x8 ap0 = *(const bf16x8*)(sPw + l16 * 72 + quad * 8);
            bf16x8 ap1 = *(const bf16x8*)(sPw + l16 * 72 + 32 + quad * 8);
            #pragma unroll
            for (int dt = 0; dt < 4; dt++) {
                const u16* vp = sVt + (dt * 16 + l16) * 72 + quad * 8;
                bf16x8 bv0 = *(const bf16x8*)(vp);
                bf16x8 bv1 = *(const bf16x8*)(vp + 32);
                acc[dt] = __builtin_amdgcn_mfma_f32_16x16x32_bf16(ap0, bv0, acc[dt], 0, 0, 0);
                acc[dt] = __builtin_amdgcn_mfma_f32_16x16x32_bf16(ap1, bv1, acc[dt], 0, 0, 0);
            }
        }

        #pragma unroll
        for (int dt = 0; dt < 4; dt++) {
            #pragma unroll
            for (int r = 0; r < 4; r++) {
                float val = acc[dt][r] / l_i[r];
                size_t idx = (size_t)(qt * 64 + wave * 16 + quad * 4 + r) * QDIM + h * 64 + dt * 16 + l16;
                o[idx] = f2b(val);
            }
        }
    }
}

// ---------------- 6. final: out = p0 + p1 + out_b + x ----------------
__global__ __launch_bounds__(256) void final_add_kernel(
    const u16* __restrict__ p0, const u16* __restrict__ p1,
    const float* __restrict__ bias, const float* __restrict__ x, float* __restrict__ out)
{
    int i = blockIdx.x * 256 + threadIdx.x;        // group of 4 elems
    int base = i * 4;
    int col = base % HID;
    float4 xo = *(const float4*)(x + base);
    float4 bi = *(const float4*)(bias + col);
    u16x4 a = ((const u16x4*)p0)[i];
    u16x4 b = ((const u16x4*)p1)[i];
    float4 r;
    r.x = b2f(a.x) + b2f(b.x) + bi.x + xo.x;
    r.y = b2f(a.y) + b2f(b.y) + bi.y + xo.y;
    r.z = b2f(a.z) + b2f(b.z) + bi.z + xo.z;
    r.w = b2f(a.w) + b2f(b.w) + bi.w + xo.w;
    *(float4*)(out + base) = r;
}

// ---------------- launch ----------------
extern "C" void kernel_launch(void* const* d_in, const int* in_sizes, int n_in,
                              void* d_out, int out_size, void* d_ws, size_t ws_size,
                              hipStream_t stream)
{
    const float* x          = (const float*)d_in[0];
    const float* sinks      = (const float*)d_in[1];
    const float* norm_scale = (const float*)d_in[2];
    const float* qkv_w      = (const float*)d_in[3];
    const float* qkv_b      = (const float*)d_in[4];
    const float* out_w      = (const float*)d_in[5];
    const float* out_b      = (const float*)d_in[6];
    float* out = (float*)d_out;

    char* ws = (char*)d_ws;
    // Phase A: t @0, qkv_w_bf @8.85M, qkvp0 @38.34M, qkvp1 @54.07M (= qkvp0 + M*N, CONTIGUOUS — split-K writes Cp + z*M*N)
    u16* t        = (u16*)(ws);                  // 8,847,360
    u16* qkv_w_bf = (u16*)(ws + 8847360);        // 29,491,200 -> 38,338,560
    u16* qkvp0    = (u16*)(ws + 38338560);       // 15,728,640 -> 54,067,200
    u16* qkvp1    = (u16*)(ws + 54067200);       // 15,728,640 -> 69,795,840  (qkvp0 + 1536*5120*2 ✓)
    float* cosT   = (float*)(ws + 69795840);     // 196,608
    float* sinT   = (float*)(ws + 69992448);     // 196,608 (total 70,189,056)
    // Phase B (after QKV gemm): k_r @0, vt @1.57M, q_r @3.15M, o @15.73M, v_r @28.31M (dead after vt),
    //   outp0 @28.31M, outp1 @37.16M (= outp0 + 1536*2880*2, CONTIGUOUS ✓ — round-5 bug: outp1 was
    //   NOT at Cp+M*N, so z=1 partial landed on out_w_bf and final_add read poison),
    //   out_w_bf @46.01M (ends 69.60M; overlays dead qkvp0/qkvp1 only).
    u16* k_r      = (u16*)(ws);                  // 1,572,864
    u16* vt       = (u16*)(ws + 1572864);        // 1,572,864 -> 3,145,728
    u16* q_r      = (u16*)(ws + 3145728);        // 12,582,912 -> 15,728,640
    u16* o        = (u16*)(ws + 15728640);       // 12,582,912 -> 28,311,552
    u16* v_r      = (u16*)(ws + 28311552);       // 1,572,864 -> 29,884,416 (consumed by vt_kernel)
    u16* outp0    = (u16*)(ws + 28311552);       // 8,847,360 -> 37,158,912 (written after v_r dead)
    u16* outp1    = (u16*)(ws + 37158912);       // 8,847,360 -> 46,006,272
    u16* out_w_bf = (u16*)(ws + 46006272);       // 23,592,960 -> 69,599,232

    rmsnorm_kernel<<<S_LEN, 256, 0, stream>>>(x, norm_scale, t);
    conv_bf16_kernel<<<(QKV_N * HID / 4 + 255) / 256, 256, 0, stream>>>(qkv_w, qkv_w_bf, QKV_N * HID / 4);
    rope_table_kernel<<<(S_LEN * 32) / 256, 256, 0, stream>>>(cosT, sinT);
    // QKV GEMM: M=1536 N=5120 K=2880, split-K 2 (1440 each, 45 iters)
    gemm_bt_split_kernel<<<dim3(QKV_N / 128, S_LEN / 128, 2), 256, 0, stream>>>(
        t, qkv_w_bf, qkvp0, S_LEN, QKV_N, HID, HID / 2);
    rope_apply_kernel<<<(S_LEN * 80 * 64) / 256, 256, 0, stream>>>(
        qkvp0, qkvp1, qkv_b, cosT, sinT, q_r, k_r, v_r);
    vt_kernel<<<dim3(S_LEN / 64, NKV), 256, 0, stream>>>(v_r, vt);
    conv_bf16_kernel<<<(HID * QDIM / 4 + 255) / 256, 256, 0, stream>>>(out_w, out_w_bf, HID * QDIM / 4);
    attn_kernel<<<dim3(12, NH), 256, 0, stream>>>(q_r, k_r, vt, sinks, o);
    // out GEMM: M=1536 N=2880 K=4096, split-K 2 (2048 each, 64 iters)
    gemm_bt_split_kernel<<<dim3((HID + 127) / 128, S_LEN / 128, 2), 256, 0, stream>>>(
        o, out_w_bf, outp0, S_LEN, HID, QDIM, QDIM / 2);
    final_add_kernel<<<S_LEN * HID / 4 / 256, 256, 0, stream>>>(outp0, outp1, out_b, x, out);
}

// Round 7
// 375.842 us; speedup vs baseline: 1.5133x; 1.0481x over previous
//
#include <hip/hip_runtime.h>
#include <hip/hip_bf16.h>
#include <math.h>

typedef unsigned short u16;
typedef __attribute__((ext_vector_type(8))) short bf16x8;
typedef __attribute__((ext_vector_type(4))) float f32x4;
typedef __attribute__((ext_vector_type(4))) u16 u16x4;

#define S_LEN   1536
#define HID     2880
#define NH      64
#define NKV     8
#define DH      64
#define QKV_N   5120   // 64*64 + 2*8*64
#define QDIM    4096   // 64*64
#define KVDIM   512    // 8*64
#define SMSCALE 0.125f
#define EPSV    1e-5f

__device__ __forceinline__ float b2f(u16 u) {
    unsigned int v = ((unsigned int)u) << 16;
    float f; __builtin_memcpy(&f, &v, 4); return f;
}
__device__ __forceinline__ u16 f2b(float f) {
    __hip_bfloat16 h = __float2bfloat16(f);
    return *reinterpret_cast<u16*>(&h);
}
__device__ __forceinline__ void gld16(const u16* g, u16* l) {
    __builtin_amdgcn_global_load_lds(
        (const __attribute__((address_space(1))) unsigned int*)g,
        (__attribute__((address_space(3))) unsigned int*)l, 16, 0, 0);
}
// s_waitcnt immediates (gfx9 encoding: vm[3:0],[15:14]; exp[6:4]; lgkm[11:8])
#define WAIT_VM4()   __builtin_amdgcn_s_waitcnt(0xF74)  // vmcnt<=4, lgkm/exp free
#define WAIT_VM0()   __builtin_amdgcn_s_waitcnt(0xF70)  // vmcnt<=0
#define WAIT_LGKM0() __builtin_amdgcn_s_waitcnt(0xC07F) // lgkmcnt<=0, vm/exp free

// ---------------- 0. fp32 -> bf16 convert (for weights) ----------------
__global__ __launch_bounds__(256) void conv_bf16_kernel(
    const float* __restrict__ src, u16* __restrict__ dst, int n4)
{
    int i = blockIdx.x * 256 + threadIdx.x;
    if (i >= n4) return;
    float4 v = ((const float4*)src)[i];
    u16x4 o;
    o.x = f2b(v.x); o.y = f2b(v.y); o.z = f2b(v.z); o.w = f2b(v.w);
    ((u16x4*)dst)[i] = o;
}

// ---------------- 1. RMSNorm (fp32 in -> bf16 out) ----------------
__global__ __launch_bounds__(256) void rmsnorm_kernel(
    const float* __restrict__ x, const float* __restrict__ ns, u16* __restrict__ t)
{
    const int s = blockIdx.x;
    const int tid = threadIdx.x;
    const float* xr = x + (size_t)s * HID;
    float ss = 0.f;
    for (int i = tid; i < HID; i += 256) { float v = xr[i]; ss += v * v; }
    for (int off = 32; off > 0; off >>= 1) ss += __shfl_down(ss, off);
    __shared__ float red[4];
    if ((tid & 63) == 0) red[tid >> 6] = ss;
    __syncthreads();
    float tot = red[0] + red[1] + red[2] + red[3];
    float scale = rsqrtf(tot / (float)HID + EPSV);
    u16* tr = t + (size_t)s * HID;
    for (int i = tid; i < HID; i += 256)
        tr[i] = f2b(xr[i] * scale * ns[i]);
}

// ---------------- 2. YaRN RoPE tables (fp64 to match ref) ----------------
__global__ __launch_bounds__(256) void rope_table_kernel(float* __restrict__ cosT, float* __restrict__ sinT)
{
    int idx = blockIdx.x * 256 + threadIdx.x;
    if (idx >= S_LEN * 32) return;
    int s = idx >> 5, i = idx & 31;
    const double PI2 = 6.283185307179586476925286766559;
    double base = 150000.0;
    double freq = pow(base, (double)(2 * i) / 64.0);
    double conc = 0.1 * log(32.0) + 1.0;
    double low  = 32.0 * log(4096.0 / (32.0 * PI2)) / log(base);
    double high = 32.0 * log(4096.0 / (1.0  * PI2)) / log(base);
    double interp = 1.0 / (32.0 * freq);
    double extrap = 1.0 / freq;
    double ramp = ((double)i - low) / (high - low);
    double msk = 1.0 - fmin(fmax(ramp, 0.0), 1.0);
    double invf = interp * (1.0 - msk) + extrap * msk;
    double ang = (double)s * invf;
    cosT[idx] = (float)(cos(ang) * conc);
    sinT[idx] = (float)(sin(ang) * conc);
}

// ---------------- 3. split-K GEMM  Cp[z][M,N](bf16) = A[M,K](bf16) * B[N,K]^T(bf16), K-chunk per z ----------------
// Double-buffered LDS + raw s_barrier + manual vmcnt (no __syncthreads drain).
// NOTE: partials for z=0,1 MUST be contiguous: Cp + z*M*N elements.
__global__ __launch_bounds__(256) void gemm_bt_split_kernel(
    const u16* __restrict__ A, const u16* __restrict__ B, u16* __restrict__ Cp,
    int M, int N, int K, int kchunk)
{
    __shared__ __align__(16) u16 sA[2][128 * 32];
    __shared__ __align__(16) u16 sB[2][128 * 32];
    const int tid  = threadIdx.x;
    const int wave = tid >> 6, lane = tid & 63;
    const int quad = lane >> 4, l16 = lane & 15;
    const int bm = blockIdx.y * 128, bn = blockIdx.x * 128;
    const int wm = (wave >> 1) * 64, wn = (wave & 1) * 64;
    const int kb = blockIdx.z * kchunk;
    u16* C = Cp + (size_t)blockIdx.z * M * N;

    const int r0   = wave * 32;
    const int lrow = lane >> 2;
    const int lcol = (lane & 3) * 8;

    const u16* gA0 = A + (size_t)(bm + r0 + lrow) * K + lcol + kb;
    const u16* gA1 = gA0 + (size_t)16 * K;
    int br0 = bn + r0 + lrow;      if (br0 > N - 1) br0 = N - 1;
    int br1 = bn + r0 + 16 + lrow; if (br1 > N - 1) br1 = N - 1;
    const u16* gB0 = B + (size_t)br0 * K + lcol + kb;
    const u16* gB1 = B + (size_t)br1 * K + lcol + kb;

    f32x4 acc[4][4];
    #pragma unroll
    for (int mt = 0; mt < 4; mt++)
        #pragma unroll
        for (int nt = 0; nt < 4; nt++)
            acc[mt][nt] = (f32x4){0.f, 0.f, 0.f, 0.f};

    auto stage = [&](int buf, int koff) {
        gld16(gA0 + koff, &sA[buf][r0 * 32]);
        gld16(gA1 + koff, &sA[buf][(r0 + 16) * 32]);
        gld16(gB0 + koff, &sB[buf][r0 * 32]);
        gld16(gB1 + koff, &sB[buf][(r0 + 16) * 32]);
    };
    auto compute = [&](int buf) {
        bf16x8 av[4], bv[4];
        #pragma unroll
        for (int mt = 0; mt < 4; mt++)
            av[mt] = *(const bf16x8*)(&sA[buf][(wm + mt * 16 + l16) * 32 + quad * 8]);
        #pragma unroll
        for (int nt = 0; nt < 4; nt++)
            bv[nt] = *(const bf16x8*)(&sB[buf][(wn + nt * 16 + l16) * 32 + quad * 8]);
        #pragma unroll
        for (int mt = 0; mt < 4; mt++)
            #pragma unroll
            for (int nt = 0; nt < 4; nt++)
                acc[mt][nt] = __builtin_amdgcn_mfma_f32_16x16x32_bf16(av[mt], bv[nt], acc[mt][nt], 0, 0, 0);
    };

    const int niter = kchunk / 32;
    stage(0, 0);
    int cur = 0;
    for (int i = 0; i < niter - 1; ++i) {
        stage(cur ^ 1, (i + 1) * 32);     // prefetch next tile (4 loads in flight on top of cur's 4)
        WAIT_VM4();                        // my cur-tile loads landed
        __builtin_amdgcn_s_barrier();      // everyone's cur-tile landed
        compute(cur);
        WAIT_LGKM0();                      // my reads of cur done
        __builtin_amdgcn_s_barrier();      // everyone's reads done -> cur may be overwritten
        cur ^= 1;
    }
    WAIT_VM0();
    __builtin_amdgcn_s_barrier();
    compute(cur);

    #pragma unroll
    for (int mt = 0; mt < 4; mt++) {
        #pragma unroll
        for (int nt = 0; nt < 4; nt++) {
            int col = bn + wn + nt * 16 + l16;
            if (col < N) {
                int row0 = bm + wm + mt * 16 + quad * 4;
                #pragma unroll
                for (int r = 0; r < 4; r++)
                    C[(size_t)(row0 + r) * N + col] = f2b(acc[mt][nt][r]);
            }
        }
    }
}

// ---------------- 4. RoPE apply + split-K reduce + bias + split to q/k/v bf16 ----------------
// Q is pre-scaled by SMSCALE (=2^-3, exact) so attention needs no per-score multiply.
__global__ __launch_bounds__(256) void rope_apply_kernel(
    const u16* __restrict__ p0, const u16* __restrict__ p1, const float* __restrict__ bias,
    const float* __restrict__ cosT, const float* __restrict__ sinT,
    u16* __restrict__ q_r, u16* __restrict__ k_r, u16* __restrict__ v_r)
{
    int idx = blockIdx.x * 256 + threadIdx.x;       // s * 5120 + hh*64 + i, hh in [0,80)
    if (idx >= S_LEN * 80 * 64) return;
    int s  = idx / 5120;
    int rem = idx - s * 5120;
    int hh = rem >> 6;
    int i  = rem & 63;
    const u16* r0p = p0 + (size_t)s * QKV_N;
    const u16* r1p = p1 + (size_t)s * QKV_N;
    #define QKVV(o) (b2f(r0p[o]) + b2f(r1p[o]) + bias[o])
    if (hh < 64) {                      // Q heads (pre-scaled by SMSCALE)
        int off = hh * 64, j = i & 31;
        float x1 = QKVV(off + j), x2 = QKVV(off + 32 + j);
        float c = cosT[s * 32 + j], sn = sinT[s * 32 + j];
        float val = (i < 32) ? (x1 * c - x2 * sn) : (x2 * c + x1 * sn);
        q_r[(size_t)s * QDIM + off + i] = f2b(val * SMSCALE);
    } else if (hh < 72) {               // K heads
        int kh = hh - 64, off = QDIM + kh * 64, j = i & 31;
        float x1 = QKVV(off + j), x2 = QKVV(off + 32 + j);
        float c = cosT[s * 32 + j], sn = sinT[s * 32 + j];
        float val = (i < 32) ? (x1 * c - x2 * sn) : (x2 * c + x1 * sn);
        k_r[(size_t)s * KVDIM + kh * 64 + i] = f2b(val);
    } else {                            // V heads (no rope)
        int vh = hh - 72, off = QDIM + KVDIM + vh * 64;
        v_r[(size_t)s * KVDIM + vh * 64 + i] = f2b(QKVV(off + i));
    }
    #undef QKVV
}

// ---------------- 4b. V transpose: v_r[s][kvh*64+d] -> vt[(kvh*64+d)][s] ----------------
__global__ __launch_bounds__(256) void vt_kernel(
    const u16* __restrict__ v_r, u16* __restrict__ vt)
{
    __shared__ u16 tile[64][72];
    const int s0 = blockIdx.x * 64;
    const int kvh = blockIdx.y;
    const int tid = threadIdx.x;
    const int r = tid >> 3;          // 0..31
    const int c = (tid & 7) * 8;     // 0..56

    #pragma unroll
    for (int rr = 0; rr < 64; rr += 32) {
        uint4 vv = *(const uint4*)(v_r + (size_t)(s0 + r + rr) * KVDIM + kvh * 64 + c);
        const u16* p = (const u16*)&vv;
        #pragma unroll
        for (int j = 0; j < 8; j++) tile[c + j][r + rr] = p[j];
    }
    __syncthreads();
    #pragma unroll
    for (int rr = 0; rr < 64; rr += 32) {
        uint4 ov;
        u16* p = (u16*)&ov;
        #pragma unroll
        for (int j = 0; j < 8; j++) p[j] = tile[r + rr][c + j];
        *(uint4*)(vt + (size_t)(kvh * 64 + r + rr) * S_LEN + s0 + c) = ov;
    }
}

// ---------------- 5. Flash attention, TRANSPOSED-SCORE form ----------------
// S^T = mfma(Kfrag, Qfrag): col(lane&15)=query, row(quad*4+reg)=key.
// Each lane owns ONE query: softmax reduction = 15 in-lane ops + 2 shfls (xor16, xor32).
// O^T = mfma(Vtfrag, Pfrag): col=query, row=d; per-lane scalar m/l/alpha.
// All LDS read expressions identical to the verified round-4/6 kernel; only
// MFMA operand order + index interpretation changed. Q pre-scaled by SMSCALE.
// Grid (12, 64): block bx does q-tiles bx and 23-bx (balanced: 25 chunks each).
__global__ __launch_bounds__(256) void attn_kernel(
    const u16* __restrict__ q_r, const u16* __restrict__ k_r, const u16* __restrict__ vt,
    const float* __restrict__ sinks, u16* __restrict__ o)
{
    __shared__ __align__(16) u16 sK[64 * 72];     // keys x d, pad 72
    __shared__ __align__(16) u16 sVt[64 * 72];    // d x keys, pad 72
    __shared__ __align__(16) u16 sP[4 * 16 * 72]; // per-wave: 16 queries x 64 keys, pad 72

    const int bx = blockIdx.x, h = blockIdx.y;
    const int kvh = h & 7;
    const int tid = threadIdx.x, wave = tid >> 6, lane = tid & 63;
    const int quad = lane >> 4, l16 = lane & 15;
    const int srow = tid >> 3;            // 0..31
    const int scol = (tid & 7) * 8;       // 0..56
    u16* sPw = sP + wave * 16 * 72;
    const float sinkv = sinks[h];

    for (int phase = 0; phase < 2; ++phase) {
        const int qt = phase ? (23 - bx) : bx;
        const int q_i = qt * 64 + wave * 16 + l16;      // this lane's query row
        const u16* qp = q_r + (size_t)q_i * QDIM + h * 64 + quad * 8;
        bf16x8 aq0 = *(const bf16x8*)(qp);
        bf16x8 aq1 = *(const bf16x8*)(qp + 32);

        float m_i = sinkv, l_i = 1.0f;
        f32x4 acc[4];
        #pragma unroll
        for (int dt = 0; dt < 4; dt++) acc[dt] = (f32x4){0.f, 0.f, 0.f, 0.f};

        const int kend = qt * 64 + 64;
        for (int j0 = 0; j0 < kend; j0 += 64) {
            __syncthreads();
            // stage K rows [j0, j0+64) and V^T cols [j0, j0+64)
            #pragma unroll
            for (int rr = 0; rr < 64; rr += 32) {
                *(uint4*)(sK + (srow + rr) * 72 + scol) =
                    *(const uint4*)(k_r + (size_t)(j0 + srow + rr) * KVDIM + kvh * 64 + scol);
                *(uint4*)(sVt + (srow + rr) * 72 + scol) =
                    *(const uint4*)(vt + (size_t)(kvh * 64 + srow + rr) * S_LEN + j0 + scol);
            }
            __syncthreads();

            // S^T: 64 keys (m, 4 tiles) x 16 queries (n) per wave
            f32x4 sc[4];
            #pragma unroll
            for (int nt = 0; nt < 4; nt++) {
                const u16* kp = sK + (nt * 16 + l16) * 72 + quad * 8;
                bf16x8 bk0 = *(const bf16x8*)(kp);
                bf16x8 bk1 = *(const bf16x8*)(kp + 32);
                f32x4 s0 = (f32x4){0.f, 0.f, 0.f, 0.f};
                s0 = __builtin_amdgcn_mfma_f32_16x16x32_bf16(bk0, aq0, s0, 0, 0, 0);  // swapped!
                s0 = __builtin_amdgcn_mfma_f32_16x16x32_bf16(bk1, aq1, s0, 0, 0, 0);
                sc[nt] = s0;
            }

            // causal mask: only the diagonal chunk (block-uniform branch)
            if (j0 + 64 == kend) {
                #pragma unroll
                for (int nt = 0; nt < 4; nt++)
                    #pragma unroll
                    for (int r = 0; r < 4; r++)
                        if (j0 + nt * 16 + quad * 4 + r > q_i) sc[nt][r] = -INFINITY;
            }

            // per-lane online softmax over 16 key-values (this lane's single query)
            float vmax = sc[0][0];
            #pragma unroll
            for (int nt = 0; nt < 4; nt++)
                #pragma unroll
                for (int r = 0; r < 4; r++) vmax = fmaxf(vmax, sc[nt][r]);
            vmax = fmaxf(vmax, __shfl_xor(vmax, 16));
            vmax = fmaxf(vmax, __shfl_xor(vmax, 32));
            float mnew = fmaxf(m_i, vmax);
            float alpha = __expf(m_i - mnew);
            float ps = 0.f;
            u16x4 pk[4];
            #pragma unroll
            for (int nt = 0; nt < 4; nt++) {
                #pragma unroll
                for (int r = 0; r < 4; r++) {
                    float p = __expf(sc[nt][r] - mnew);
                    ps += p;
                    pk[nt][r] = f2b(p);
                }
            }
            ps += __shfl_xor(ps, 16);
            ps += __shfl_xor(ps, 32);
            l_i = l_i * alpha + ps;
            m_i = mnew;
            // P[q][key]: 4 contiguous keys per (nt,quad) -> packed 8B stores
            #pragma unroll
            for (int nt = 0; nt < 4; nt++)
                *(u16x4*)(sPw + l16 * 72 + nt * 16 + quad * 4) = pk[nt];
            #pragma unroll
            for (int dt = 0; dt < 4; dt++)
                #pragma unroll
                for (int r = 0; r < 4; r++) acc[dt][r] *= alpha;
            __threadfence_block();   // order sP writes before cross-lane reads (wave-internal)

            // O^T += V^T (64xd as A) * P (16q x 64k as B)
            bf16x8 ap0 = *(const bf16x8*)(sPw + l16 * 72 + quad * 8);
            bf16x8 ap1 = *(const bf16x8*)(sPw + l16 * 72 + 32 + quad * 8);
            #pragma unroll
            for (int dt = 0; dt < 4; dt++) {
                const u16* vp = sVt + (dt * 16 + l16) * 72 + quad * 8;
                bf16x8 bv0 = *(const bf16x8*)(vp);
                bf16x8 bv1 = *(const bf16x8*)(vp + 32);
                acc[dt] = __builtin_amdgcn_mfma_f32_16x16x32_bf16(bv0, ap0, acc[dt], 0, 0, 0);  // swapped!
                acc[dt] = __builtin_amdgcn_mfma_f32_16x16x32_bf16(bv1, ap1, acc[dt], 0, 0, 0);
            }
        }

        // O^T: col=query(l16) = this lane's q_i; row = d = dt*16 + quad*4 + r (contiguous in r)
        float inv = 1.0f / l_i;
        #pragma unroll
        for (int dt = 0; dt < 4; dt++) {
            u16x4 ov;
            #pragma unroll
            for (int r = 0; r < 4; r++) ov[r] = f2b(acc[dt][r] * inv);
            *(u16x4*)(o + (size_t)q_i * QDIM + h * 64 + dt * 16 + quad * 4) = ov;
        }
    }
}

// ---------------- 6. final: out = p0 + p1 + out_b + x ----------------
__global__ __launch_bounds__(256) void final_add_kernel(
    const u16* __restrict__ p0, const u16* __restrict__ p1,
    const float* __restrict__ bias, const float* __restrict__ x, float* __restrict__ out)
{
    int i = blockIdx.x * 256 + threadIdx.x;        // group of 4 elems
    int base = i * 4;
    int col = base % HID;
    float4 xo = *(const float4*)(x + base);
    float4 bi = *(const float4*)(bias + col);
    u16x4 a = ((const u16x4*)p0)[i];
    u16x4 b = ((const u16x4*)p1)[i];
    float4 r;
    r.x = b2f(a.x) + b2f(b.x) + bi.x + xo.x;
    r.y = b2f(a.y) + b2f(b.y) + bi.y + xo.y;
    r.z = b2f(a.z) + b2f(b.z) + bi.z + xo.z;
    r.w = b2f(a.w) + b2f(b.w) + bi.w + xo.w;
    *(float4*)(out + base) = r;
}

// ---------------- launch ----------------
extern "C" void kernel_launch(void* const* d_in, const int* in_sizes, int n_in,
                              void* d_out, int out_size, void* d_ws, size_t ws_size,
                              hipStream_t stream)
{
    const float* x          = (const float*)d_in[0];
    const float* sinks      = (const float*)d_in[1];
    const float* norm_scale = (const float*)d_in[2];
    const float* qkv_w      = (const float*)d_in[3];
    const float* qkv_b      = (const float*)d_in[4];
    const float* out_w      = (const float*)d_in[5];
    const float* out_b      = (const float*)d_in[6];
    float* out = (float*)d_out;

    char* ws = (char*)d_ws;
    // Phase A: t @0, qkv_w_bf @8.85M, qkvp0 @38.34M, qkvp1 @54.07M (= qkvp0 + M*N, CONTIGUOUS)
    u16* t        = (u16*)(ws);                  // 8,847,360
    u16* qkv_w_bf = (u16*)(ws + 8847360);        // 29,491,200 -> 38,338,560
    u16* qkvp0    = (u16*)(ws + 38338560);       // 15,728,640 -> 54,067,200
    u16* qkvp1    = (u16*)(ws + 54067200);       // 15,728,640 -> 69,795,840  (qkvp0 + 1536*5120*2 ✓)
    float* cosT   = (float*)(ws + 69795840);     // 196,608
    float* sinT   = (float*)(ws + 69992448);     // 196,608 (total 70,189,056)
    // Phase B: k_r @0, vt @1.57M, q_r @3.15M, o @15.73M, v_r @28.31M (dead after vt),
    //   outp0 @28.31M, outp1 @37.16M (= outp0 + 1536*2880*2, CONTIGUOUS ✓),
    //   out_w_bf @46.01M (ends 69.60M; overlays dead qkvp0/qkvp1 only).
    u16* k_r      = (u16*)(ws);                  // 1,572,864
    u16* vt       = (u16*)(ws + 1572864);        // 1,572,864 -> 3,145,728
    u16* q_r      = (u16*)(ws + 3145728);        // 12,582,912 -> 15,728,640
    u16* o        = (u16*)(ws + 15728640);       // 12,582,912 -> 28,311,552
    u16* v_r      = (u16*)(ws + 28311552);       // 1,572,864 -> 29,884,416 (consumed by vt_kernel)
    u16* outp0    = (u16*)(ws + 28311552);       // 8,847,360 -> 37,158,912 (written after v_r dead)
    u16* outp1    = (u16*)(ws + 37158912);       // 8,847,360 -> 46,006,272
    u16* out_w_bf = (u16*)(ws + 46006272);       // 23,592,960 -> 69,599,232

    rmsnorm_kernel<<<S_LEN, 256, 0, stream>>>(x, norm_scale, t);
    conv_bf16_kernel<<<(QKV_N * HID / 4 + 255) / 256, 256, 0, stream>>>(qkv_w, qkv_w_bf, QKV_N * HID / 4);
    rope_table_kernel<<<(S_LEN * 32) / 256, 256, 0, stream>>>(cosT, sinT);
    // QKV GEMM: M=1536 N=5120 K=2880, split-K 2 (1440 each, 45 iters)
    gemm_bt_split_kernel<<<dim3(QKV_N / 128, S_LEN / 128, 2), 256, 0, stream>>>(
        t, qkv_w_bf, qkvp0, S_LEN, QKV_N, HID, HID / 2);
    rope_apply_kernel<<<(S_LEN * 80 * 64) / 256, 256, 0, stream>>>(
        qkvp0, qkvp1, qkv_b, cosT, sinT, q_r, k_r, v_r);
    vt_kernel<<<dim3(S_LEN / 64, NKV), 256, 0, stream>>>(v_r, vt);
    conv_bf16_kernel<<<(HID * QDIM / 4 + 255) / 256, 256, 0, stream>>>(out_w, out_w_bf, HID * QDIM / 4);
    attn_kernel<<<dim3(12, NH), 256, 0, stream>>>(q_r, k_r, vt, sinks, o);
    // out GEMM: M=1536 N=2880 K=4096, split-K 2 (2048 each, 64 iters)
    gemm_bt_split_kernel<<<dim3((HID + 127) / 128, S_LEN / 128, 2), 256, 0, stream>>>(
        o, out_w_bf, outp0, S_LEN, HID, QDIM, QDIM / 2);
    final_add_kernel<<<S_LEN * HID / 4 / 256, 256, 0, stream>>>(outp0, outp1, out_b, x, out);
}

// Round 8
// 368.077 us; speedup vs baseline: 1.5452x; 1.0211x over previous
//
#include <hip/hip_runtime.h>
#include <hip/hip_bf16.h>
#include <math.h>

typedef unsigned short u16;
typedef __attribute__((ext_vector_type(8))) short bf16x8;
typedef __attribute__((ext_vector_type(4))) float f32x4;
typedef __attribute__((ext_vector_type(4))) u16 u16x4;

#define S_LEN   1536
#define HID     2880
#define NH      64
#define NKV     8
#define DH      64
#define QKV_N   5120   // 64*64 + 2*8*64
#define QDIM    4096   // 64*64
#define KVDIM   512    // 8*64
#define SMSCALE 0.125f
#define EPSV    1e-5f

__device__ __forceinline__ float b2f(u16 u) {
    unsigned int v = ((unsigned int)u) << 16;
    float f; __builtin_memcpy(&f, &v, 4); return f;
}
__device__ __forceinline__ u16 f2b(float f) {
    __hip_bfloat16 h = __float2bfloat16(f);
    return *reinterpret_cast<u16*>(&h);
}
__device__ __forceinline__ void gld16(const u16* g, u16* l) {
    __builtin_amdgcn_global_load_lds(
        (const __attribute__((address_space(1))) unsigned int*)g,
        (__attribute__((address_space(3))) unsigned int*)l, 16, 0, 0);
}
// s_waitcnt immediates (gfx9 encoding: vm[3:0],[15:14]; exp[6:4]; lgkm[11:8])
#define WAIT_VM4()   __builtin_amdgcn_s_waitcnt(0xF74)  // vmcnt<=4, lgkm/exp free
#define WAIT_VM0()   __builtin_amdgcn_s_waitcnt(0xF70)  // vmcnt<=0
#define WAIT_LGKM0() __builtin_amdgcn_s_waitcnt(0xC07F) // lgkmcnt<=0, vm/exp free

// ---------------- 0. fp32 -> bf16 convert (for weights) ----------------
__global__ __launch_bounds__(256) void conv_bf16_kernel(
    const float* __restrict__ src, u16* __restrict__ dst, int n4)
{
    int i = blockIdx.x * 256 + threadIdx.x;
    if (i >= n4) return;
    float4 v = ((const float4*)src)[i];
    u16x4 o;
    o.x = f2b(v.x); o.y = f2b(v.y); o.z = f2b(v.z); o.w = f2b(v.w);
    ((u16x4*)dst)[i] = o;
}

// ---------------- 1. RMSNorm (fp32 in -> bf16 out) ----------------
__global__ __launch_bounds__(256) void rmsnorm_kernel(
    const float* __restrict__ x, const float* __restrict__ ns, u16* __restrict__ t)
{
    const int s = blockIdx.x;
    const int tid = threadIdx.x;
    const float* xr = x + (size_t)s * HID;
    float ss = 0.f;
    for (int i = tid; i < HID; i += 256) { float v = xr[i]; ss += v * v; }
    for (int off = 32; off > 0; off >>= 1) ss += __shfl_down(ss, off);
    __shared__ float red[4];
    if ((tid & 63) == 0) red[tid >> 6] = ss;
    __syncthreads();
    float tot = red[0] + red[1] + red[2] + red[3];
    float scale = rsqrtf(tot / (float)HID + EPSV);
    u16* tr = t + (size_t)s * HID;
    for (int i = tid; i < HID; i += 256)
        tr[i] = f2b(xr[i] * scale * ns[i]);
}

// ---------------- 2. YaRN RoPE tables (fp64 to match ref) ----------------
__global__ __launch_bounds__(256) void rope_table_kernel(float* __restrict__ cosT, float* __restrict__ sinT)
{
    int idx = blockIdx.x * 256 + threadIdx.x;
    if (idx >= S_LEN * 32) return;
    int s = idx >> 5, i = idx & 31;
    const double PI2 = 6.283185307179586476925286766559;
    double base = 150000.0;
    double freq = pow(base, (double)(2 * i) / 64.0);
    double conc = 0.1 * log(32.0) + 1.0;
    double low  = 32.0 * log(4096.0 / (32.0 * PI2)) / log(base);
    double high = 32.0 * log(4096.0 / (1.0  * PI2)) / log(base);
    double interp = 1.0 / (32.0 * freq);
    double extrap = 1.0 / freq;
    double ramp = ((double)i - low) / (high - low);
    double msk = 1.0 - fmin(fmax(ramp, 0.0), 1.0);
    double invf = interp * (1.0 - msk) + extrap * msk;
    double ang = (double)s * invf;
    cosT[idx] = (float)(cos(ang) * conc);
    sinT[idx] = (float)(sin(ang) * conc);
}

// ---------------- 3. split-K GEMM  Cp[z][M,N](bf16) = A[M,K](bf16) * B[N,K]^T(bf16), K-chunk per z ----------------
// Double-buffered LDS + raw s_barrier + manual vmcnt (no __syncthreads drain).
// XCD-cell swizzle: grid must be (4*nq, 2*mh, z). XCD c (= lin%8, round-robin heuristic)
// owns N-quarter (c&3) x M-half (c>>2); M-fastest within the cell keeps the per-strip
// working set (~2.6MB) inside the 4MiB XCD L2 -> B fetched ~2x, A ~4x instead of ~8x.
// NOTE: partials for z=0,1 MUST be contiguous: Cp + z*M*N elements.
__global__ __launch_bounds__(256) void gemm_bt_split_kernel(
    const u16* __restrict__ A, const u16* __restrict__ B, u16* __restrict__ Cp,
    int M, int N, int K, int kchunk, int nq, int mh)
{
    __shared__ __align__(16) u16 sA[2][128 * 32];
    __shared__ __align__(16) u16 sB[2][128 * 32];
    const int tid  = threadIdx.x;
    const int wave = tid >> 6, lane = tid & 63;
    const int quad = lane >> 4, l16 = lane & 15;

    const int lin   = blockIdx.x + gridDim.x * blockIdx.y;
    const int c     = lin & 7, slot = lin >> 3;
    const int strip = slot / mh, mm = slot - strip * mh;
    const int ntile = (c & 3) * nq + strip;
    const int mtile = (c >> 2) * mh + mm;
    const int bm = mtile * 128, bn = ntile * 128;

    const int wm = (wave >> 1) * 64, wn = (wave & 1) * 64;
    const int kb = blockIdx.z * kchunk;
    u16* C = Cp + (size_t)blockIdx.z * M * N;

    const int r0   = wave * 32;
    const int lrow = lane >> 2;
    const int lcol = (lane & 3) * 8;

    const u16* gA0 = A + (size_t)(bm + r0 + lrow) * K + lcol + kb;
    const u16* gA1 = gA0 + (size_t)16 * K;
    int br0 = bn + r0 + lrow;      if (br0 > N - 1) br0 = N - 1;
    int br1 = bn + r0 + 16 + lrow; if (br1 > N - 1) br1 = N - 1;
    const u16* gB0 = B + (size_t)br0 * K + lcol + kb;
    const u16* gB1 = B + (size_t)br1 * K + lcol + kb;

    f32x4 acc[4][4];
    #pragma unroll
    for (int mt = 0; mt < 4; mt++)
        #pragma unroll
        for (int nt = 0; nt < 4; nt++)
            acc[mt][nt] = (f32x4){0.f, 0.f, 0.f, 0.f};

    auto stage = [&](int buf, int koff) {
        gld16(gA0 + koff, &sA[buf][r0 * 32]);
        gld16(gA1 + koff, &sA[buf][(r0 + 16) * 32]);
        gld16(gB0 + koff, &sB[buf][r0 * 32]);
        gld16(gB1 + koff, &sB[buf][(r0 + 16) * 32]);
    };
    auto compute = [&](int buf) {
        bf16x8 av[4], bv[4];
        #pragma unroll
        for (int mt = 0; mt < 4; mt++)
            av[mt] = *(const bf16x8*)(&sA[buf][(wm + mt * 16 + l16) * 32 + quad * 8]);
        #pragma unroll
        for (int nt = 0; nt < 4; nt++)
            bv[nt] = *(const bf16x8*)(&sB[buf][(wn + nt * 16 + l16) * 32 + quad * 8]);
        #pragma unroll
        for (int mt = 0; mt < 4; mt++)
            #pragma unroll
            for (int nt = 0; nt < 4; nt++)
                acc[mt][nt] = __builtin_amdgcn_mfma_f32_16x16x32_bf16(av[mt], bv[nt], acc[mt][nt], 0, 0, 0);
    };

    const int niter = kchunk / 32;
    stage(0, 0);
    int cur = 0;
    for (int i = 0; i < niter - 1; ++i) {
        stage(cur ^ 1, (i + 1) * 32);     // prefetch next tile (4 loads in flight on top of cur's 4)
        WAIT_VM4();                        // my cur-tile loads landed
        __builtin_amdgcn_s_barrier();      // everyone's cur-tile landed
        compute(cur);
        WAIT_LGKM0();                      // my reads of cur done
        __builtin_amdgcn_s_barrier();      // everyone's reads done -> cur may be overwritten
        cur ^= 1;
    }
    WAIT_VM0();
    __builtin_amdgcn_s_barrier();
    compute(cur);

    #pragma unroll
    for (int mt = 0; mt < 4; mt++) {
        #pragma unroll
        for (int nt = 0; nt < 4; nt++) {
            int col = bn + wn + nt * 16 + l16;
            if (col < N) {
                int row0 = bm + wm + mt * 16 + quad * 4;
                #pragma unroll
                for (int r = 0; r < 4; r++)
                    C[(size_t)(row0 + r) * N + col] = f2b(acc[mt][nt][r]);
            }
        }
    }
}

// ---------------- 4. RoPE apply + split-K reduce + bias + split to q/k/v bf16 ----------------
// Q is pre-scaled by SMSCALE (=2^-3, exact) so attention needs no per-score multiply.
__global__ __launch_bounds__(256) void rope_apply_kernel(
    const u16* __restrict__ p0, const u16* __restrict__ p1, const float* __restrict__ bias,
    const float* __restrict__ cosT, const float* __restrict__ sinT,
    u16* __restrict__ q_r, u16* __restrict__ k_r, u16* __restrict__ v_r)
{
    int idx = blockIdx.x * 256 + threadIdx.x;       // s * 5120 + hh*64 + i, hh in [0,80)
    if (idx >= S_LEN * 80 * 64) return;
    int s  = idx / 5120;
    int rem = idx - s * 5120;
    int hh = rem >> 6;
    int i  = rem & 63;
    const u16* r0p = p0 + (size_t)s * QKV_N;
    const u16* r1p = p1 + (size_t)s * QKV_N;
    #define QKVV(o) (b2f(r0p[o]) + b2f(r1p[o]) + bias[o])
    if (hh < 64) {                      // Q heads (pre-scaled by SMSCALE)
        int off = hh * 64, j = i & 31;
        float x1 = QKVV(off + j), x2 = QKVV(off + 32 + j);
        float c = cosT[s * 32 + j], sn = sinT[s * 32 + j];
        float val = (i < 32) ? (x1 * c - x2 * sn) : (x2 * c + x1 * sn);
        q_r[(size_t)s * QDIM + off + i] = f2b(val * SMSCALE);
    } else if (hh < 72) {               // K heads
        int kh = hh - 64, off = QDIM + kh * 64, j = i & 31;
        float x1 = QKVV(off + j), x2 = QKVV(off + 32 + j);
        float c = cosT[s * 32 + j], sn = sinT[s * 32 + j];
        float val = (i < 32) ? (x1 * c - x2 * sn) : (x2 * c + x1 * sn);
        k_r[(size_t)s * KVDIM + kh * 64 + i] = f2b(val);
    } else {                            // V heads (no rope)
        int vh = hh - 72, off = QDIM + KVDIM + vh * 64;
        v_r[(size_t)s * KVDIM + vh * 64 + i] = f2b(QKVV(off + i));
    }
    #undef QKVV
}

// ---------------- 4b. V transpose: v_r[s][kvh*64+d] -> vt[(kvh*64+d)][s] ----------------
__global__ __launch_bounds__(256) void vt_kernel(
    const u16* __restrict__ v_r, u16* __restrict__ vt)
{
    __shared__ u16 tile[64][72];
    const int s0 = blockIdx.x * 64;
    const int kvh = blockIdx.y;
    const int tid = threadIdx.x;
    const int r = tid >> 3;          // 0..31
    const int c = (tid & 7) * 8;     // 0..56

    #pragma unroll
    for (int rr = 0; rr < 64; rr += 32) {
        uint4 vv = *(const uint4*)(v_r + (size_t)(s0 + r + rr) * KVDIM + kvh * 64 + c);
        const u16* p = (const u16*)&vv;
        #pragma unroll
        for (int j = 0; j < 8; j++) tile[c + j][r + rr] = p[j];
    }
    __syncthreads();
    #pragma unroll
    for (int rr = 0; rr < 64; rr += 32) {
        uint4 ov;
        u16* p = (u16*)&ov;
        #pragma unroll
        for (int j = 0; j < 8; j++) p[j] = tile[r + rr][c + j];
        *(uint4*)(vt + (size_t)(kvh * 64 + r + rr) * S_LEN + s0 + c) = ov;
    }
}

// ---------------- 5. Flash attention, TRANSPOSED-SCORE form ----------------
// S^T = mfma(Kfrag, Qfrag): col(lane&15)=query, row(quad*4+reg)=key.
// Each lane owns ONE query: softmax reduction = 15 in-lane ops + 2 shfls (xor16, xor32).
// O^T = mfma(Vtfrag, Pfrag): col=query, row=d; per-lane scalar m/l/alpha.
// Q pre-scaled by SMSCALE. Grid (12, 64): block bx does q-tiles bx and 23-bx.
__global__ __launch_bounds__(256) void attn_kernel(
    const u16* __restrict__ q_r, const u16* __restrict__ k_r, const u16* __restrict__ vt,
    const float* __restrict__ sinks, u16* __restrict__ o)
{
    __shared__ __align__(16) u16 sK[64 * 72];     // keys x d, pad 72
    __shared__ __align__(16) u16 sVt[64 * 72];    // d x keys, pad 72
    __shared__ __align__(16) u16 sP[4 * 16 * 72]; // per-wave: 16 queries x 64 keys, pad 72

    const int bx = blockIdx.x, h = blockIdx.y;
    const int kvh = h & 7;
    const int tid = threadIdx.x, wave = tid >> 6, lane = tid & 63;
    const int quad = lane >> 4, l16 = lane & 15;
    const int srow = tid >> 3;            // 0..31
    const int scol = (tid & 7) * 8;       // 0..56
    u16* sPw = sP + wave * 16 * 72;
    const float sinkv = sinks[h];

    for (int phase = 0; phase < 2; ++phase) {
        const int qt = phase ? (23 - bx) : bx;
        const int q_i = qt * 64 + wave * 16 + l16;      // this lane's query row
        const u16* qp = q_r + (size_t)q_i * QDIM + h * 64 + quad * 8;
        bf16x8 aq0 = *(const bf16x8*)(qp);
        bf16x8 aq1 = *(const bf16x8*)(qp + 32);

        float m_i = sinkv, l_i = 1.0f;
        f32x4 acc[4];
        #pragma unroll
        for (int dt = 0; dt < 4; dt++) acc[dt] = (f32x4){0.f, 0.f, 0.f, 0.f};

        const int kend = qt * 64 + 64;
        for (int j0 = 0; j0 < kend; j0 += 64) {
            __syncthreads();
            // stage K rows [j0, j0+64) and V^T cols [j0, j0+64)
            #pragma unroll
            for (int rr = 0; rr < 64; rr += 32) {
                *(uint4*)(sK + (srow + rr) * 72 + scol) =
                    *(const uint4*)(k_r + (size_t)(j0 + srow + rr) * KVDIM + kvh * 64 + scol);
                *(uint4*)(sVt + (srow + rr) * 72 + scol) =
                    *(const uint4*)(vt + (size_t)(kvh * 64 + srow + rr) * S_LEN + j0 + scol);
            }
            __syncthreads();

            // S^T: 64 keys (m, 4 tiles) x 16 queries (n) per wave
            f32x4 sc[4];
            #pragma unroll
            for (int nt = 0; nt < 4; nt++) {
                const u16* kp = sK + (nt * 16 + l16) * 72 + quad * 8;
                bf16x8 bk0 = *(const bf16x8*)(kp);
                bf16x8 bk1 = *(const bf16x8*)(kp + 32);
                f32x4 s0 = (f32x4){0.f, 0.f, 0.f, 0.f};
                s0 = __builtin_amdgcn_mfma_f32_16x16x32_bf16(bk0, aq0, s0, 0, 0, 0);  // swapped!
                s0 = __builtin_amdgcn_mfma_f32_16x16x32_bf16(bk1, aq1, s0, 0, 0, 0);
                sc[nt] = s0;
            }

            // causal mask: only the diagonal chunk (block-uniform branch)
            if (j0 + 64 == kend) {
                #pragma unroll
                for (int nt = 0; nt < 4; nt++)
                    #pragma unroll
                    for (int r = 0; r < 4; r++)
                        if (j0 + nt * 16 + quad * 4 + r > q_i) sc[nt][r] = -INFINITY;
            }

            // per-lane online softmax over 16 key-values (this lane's single query)
            float vmax = sc[0][0];
            #pragma unroll
            for (int nt = 0; nt < 4; nt++)
                #pragma unroll
                for (int r = 0; r < 4; r++) vmax = fmaxf(vmax, sc[nt][r]);
            vmax = fmaxf(vmax, __shfl_xor(vmax, 16));
            vmax = fmaxf(vmax, __shfl_xor(vmax, 32));
            float mnew = fmaxf(m_i, vmax);
            float alpha = __expf(m_i - mnew);
            float ps = 0.f;
            u16x4 pk[4];
            #pragma unroll
            for (int nt = 0; nt < 4; nt++) {
                #pragma unroll
                for (int r = 0; r < 4; r++) {
                    float p = __expf(sc[nt][r] - mnew);
                    ps += p;
                    pk[nt][r] = f2b(p);
                }
            }
            ps += __shfl_xor(ps, 16);
            ps += __shfl_xor(ps, 32);
            l_i = l_i * alpha + ps;
            m_i = mnew;
            // P[q][key]: 4 contiguous keys per (nt,quad) -> packed 8B stores
            #pragma unroll
            for (int nt = 0; nt < 4; nt++)
                *(u16x4*)(sPw + l16 * 72 + nt * 16 + quad * 4) = pk[nt];
            #pragma unroll
            for (int dt = 0; dt < 4; dt++)
                #pragma unroll
                for (int r = 0; r < 4; r++) acc[dt][r] *= alpha;
            __threadfence_block();   // order sP writes before cross-lane reads (wave-internal)

            // O^T += V^T (64xd as A) * P (16q x 64k as B)
            bf16x8 ap0 = *(const bf16x8*)(sPw + l16 * 72 + quad * 8);
            bf16x8 ap1 = *(const bf16x8*)(sPw + l16 * 72 + 32 + quad * 8);
            #pragma unroll
            for (int dt = 0; dt < 4; dt++) {
                const u16* vp = sVt + (dt * 16 + l16) * 72 + quad * 8;
                bf16x8 bv0 = *(const bf16x8*)(vp);
                bf16x8 bv1 = *(const bf16x8*)(vp + 32);
                acc[dt] = __builtin_amdgcn_mfma_f32_16x16x32_bf16(bv0, ap0, acc[dt], 0, 0, 0);  // swapped!
                acc[dt] = __builtin_amdgcn_mfma_f32_16x16x32_bf16(bv1, ap1, acc[dt], 0, 0, 0);
            }
        }

        // O^T: col=query(l16) = this lane's q_i; row = d = dt*16 + quad*4 + r (contiguous in r)
        float inv = 1.0f / l_i;
        #pragma unroll
        for (int dt = 0; dt < 4; dt++) {
            u16x4 ov;
            #pragma unroll
            for (int r = 0; r < 4; r++) ov[r] = f2b(acc[dt][r] * inv);
            *(u16x4*)(o + (size_t)q_i * QDIM + h * 64 + dt * 16 + quad * 4) = ov;
        }
    }
}

// ---------------- 6. final: out = p0 + p1 + out_b + x ----------------
__global__ __launch_bounds__(256) void final_add_kernel(
    const u16* __restrict__ p0, const u16* __restrict__ p1,
    const float* __restrict__ bias, const float* __restrict__ x, float* __restrict__ out)
{
    int i = blockIdx.x * 256 + threadIdx.x;        // group of 4 elems
    int base = i * 4;
    int col = base % HID;
    float4 xo = *(const float4*)(x + base);
    float4 bi = *(const float4*)(bias + col);
    u16x4 a = ((const u16x4*)p0)[i];
    u16x4 b = ((const u16x4*)p1)[i];
    float4 r;
    r.x = b2f(a.x) + b2f(b.x) + bi.x + xo.x;
    r.y = b2f(a.y) + b2f(b.y) + bi.y + xo.y;
    r.z = b2f(a.z) + b2f(b.z) + bi.z + xo.z;
    r.w = b2f(a.w) + b2f(b.w) + bi.w + xo.w;
    *(float4*)(out + base) = r;
}

// ---------------- launch ----------------
extern "C" void kernel_launch(void* const* d_in, const int* in_sizes, int n_in,
                              void* d_out, int out_size, void* d_ws, size_t ws_size,
                              hipStream_t stream)
{
    const float* x          = (const float*)d_in[0];
    const float* sinks      = (const float*)d_in[1];
    const float* norm_scale = (const float*)d_in[2];
    const float* qkv_w      = (const float*)d_in[3];
    const float* qkv_b      = (const float*)d_in[4];
    const float* out_w      = (const float*)d_in[5];
    const float* out_b      = (const float*)d_in[6];
    float* out = (float*)d_out;

    char* ws = (char*)d_ws;
    // Phase A: t @0, qkv_w_bf @8.85M, qkvp0 @38.34M, qkvp1 @54.07M (= qkvp0 + M*N, CONTIGUOUS)
    u16* t        = (u16*)(ws);                  // 8,847,360
    u16* qkv_w_bf = (u16*)(ws + 8847360);        // 29,491,200 -> 38,338,560
    u16* qkvp0    = (u16*)(ws + 38338560);       // 15,728,640 -> 54,067,200
    u16* qkvp1    = (u16*)(ws + 54067200);       // 15,728,640 -> 69,795,840  (qkvp0 + 1536*5120*2 ✓)
    float* cosT   = (float*)(ws + 69795840);     // 196,608
    float* sinT   = (float*)(ws + 69992448);     // 196,608 (total 70,189,056)
    // Phase B: k_r @0, vt @1.57M, q_r @3.15M, o @15.73M, v_r @28.31M (dead after vt),
    //   outp0 @28.31M, outp1 @37.16M (= outp0 + 1536*2880*2, CONTIGUOUS ✓),
    //   out_w_bf @46.01M (ends 69.60M; overlays dead qkvp0/qkvp1 only).
    u16* k_r      = (u16*)(ws);                  // 1,572,864
    u16* vt       = (u16*)(ws + 1572864);        // 1,572,864 -> 3,145,728
    u16* q_r      = (u16*)(ws + 3145728);        // 12,582,912 -> 15,728,640
    u16* o        = (u16*)(ws + 15728640);       // 12,582,912 -> 28,311,552
    u16* v_r      = (u16*)(ws + 28311552);       // 1,572,864 -> 29,884,416 (consumed by vt_kernel)
    u16* outp0    = (u16*)(ws + 28311552);       // 8,847,360 -> 37,158,912 (written after v_r dead)
    u16* outp1    = (u16*)(ws + 37158912);       // 8,847,360 -> 46,006,272
    u16* out_w_bf = (u16*)(ws + 46006272);       // 23,592,960 -> 69,599,232

    rmsnorm_kernel<<<S_LEN, 256, 0, stream>>>(x, norm_scale, t);
    conv_bf16_kernel<<<(QKV_N * HID / 4 + 255) / 256, 256, 0, stream>>>(qkv_w, qkv_w_bf, QKV_N * HID / 4);
    rope_table_kernel<<<(S_LEN * 32) / 256, 256, 0, stream>>>(cosT, sinT);
    // QKV GEMM: M=1536 N=5120 K=2880, split-K 2 (1440 each, 45 iters)
    // grid (40,12,2): nq=10 (N-quarter), mh=6 (M-half) -> XCD-cell swizzle bijection
    gemm_bt_split_kernel<<<dim3(QKV_N / 128, S_LEN / 128, 2), 256, 0, stream>>>(
        t, qkv_w_bf, qkvp0, S_LEN, QKV_N, HID, HID / 2, 10, 6);
    rope_apply_kernel<<<(S_LEN * 80 * 64) / 256, 256, 0, stream>>>(
        qkvp0, qkvp1, qkv_b, cosT, sinT, q_r, k_r, v_r);
    vt_kernel<<<dim3(S_LEN / 64, NKV), 256, 0, stream>>>(v_r, vt);
    conv_bf16_kernel<<<(HID * QDIM / 4 + 255) / 256, 256, 0, stream>>>(out_w, out_w_bf, HID * QDIM / 4);
    attn_kernel<<<dim3(12, NH), 256, 0, stream>>>(q_r, k_r, vt, sinks, o);
    // out GEMM: M=1536 N=2880 K=4096, split-K 2 (2048 each, 64 iters)
    // N-tiles padded 23->24 (pad tile reads clamped rows, writes nothing): nq=6, mh=6
    gemm_bt_split_kernel<<<dim3(24, S_LEN / 128, 2), 256, 0, stream>>>(
        o, out_w_bf, outp0, S_LEN, HID, QDIM, QDIM / 2, 6, 6);
    final_add_kernel<<<S_LEN * HID / 4 / 256, 256, 0, stream>>>(outp0, outp1, out_b, x, out);
}